// Round 11
// baseline (642.737 us; speedup 1.0000x reference)
//
#include <hip/hip_runtime.h>

#define N_NODES 50000
#define E_EDGES 1600000
#define E2 (E_EDGES + N_NODES)   // 1,650,000 with self loops
#define HEADS 4
#define F 256
#define OUTC 10
#define BN_EPS 1e-5f
#define NEG_SLOPE 0.2f
#define NSLICE 64                // stats atomic-spreading slices
#define SCAN_T 1024
#define SCAN_CHUNK ((N_NODES + SCAN_T - 1) / SCAN_T)   // 49

// mega_prep block ranges
#define CXB (N_NODES * 128 / 4 / 256)        // 6250 convert_x blocks
#define CWB 128                               // convert_w1T blocks
#define CDB ((E2 + 255) / 256)                // 6446 count_deg blocks

static_assert(N_NODES % 4 == 0, "grid_nw exact");

typedef __attribute__((ext_vector_type(8))) short short8;
typedef __attribute__((ext_vector_type(4))) float f32x4;

__device__ __forceinline__ unsigned short f2bf(float f) {
    unsigned int u = __float_as_uint(f);
    unsigned int r = (u + 0x7fffu + ((u >> 16) & 1u)) >> 16;
    return (unsigned short)r;
}
__device__ __forceinline__ float bf2f(unsigned short b) {
    return __uint_as_float(((unsigned int)b) << 16);
}

// ---- fused prep: convert_x | convert_w1T | count_deg (branch on block) --
__global__ __launch_bounds__(256) void mega_prep(
    const float* __restrict__ X, unsigned short* __restrict__ Xb,
    const float* __restrict__ W1, unsigned short* __restrict__ WT,
    const int* __restrict__ eidx, int* __restrict__ deg)
{
    const int b = blockIdx.x;
    const int t = threadIdx.x;
    if (b < CXB) {
        const int i = b * 256 + t;                 // float4 index, exact
        float4 v = reinterpret_cast<const float4*>(X)[i];
        ushort4 o = { f2bf(v.x), f2bf(v.y), f2bf(v.z), f2bf(v.w) };
        reinterpret_cast<ushort4*>(Xb)[i] = o;
    } else if (b < CXB + CWB) {
        const int k = b - CXB;                     // W1 row
        WT[t * 128 + k] = f2bf(W1[k * 256 + t]);
    } else {
        const int e = (b - CXB - CWB) * 256 + t;
        if (e < E2) {
            int dst = (e < E_EDGES) ? eidx[E_EDGES + e] : e - E_EDGES;
            atomicAdd(&deg[dst], 1);
        }
    }
}

// ---- single-block exclusive scan (R2-proven) ----
__global__ __launch_bounds__(SCAN_T) void scan_deg(
    const int* __restrict__ deg, int* __restrict__ rowptr)
{
    __shared__ int part[SCAN_T];
    const int t = threadIdx.x;
    const int base = t * SCAN_CHUNK;
    int s = 0;
    for (int i = 0; i < SCAN_CHUNK; i++) {
        int idx = base + i;
        if (idx < N_NODES) s += deg[idx];
    }
    part[t] = s;
    __syncthreads();
    for (int off = 1; off < SCAN_T; off <<= 1) {
        int v = (t >= off) ? part[t - off] : 0;
        __syncthreads();
        part[t] += v;
        __syncthreads();
    }
    int run = (t == 0) ? 0 : part[t - 1];
    for (int i = 0; i < SCAN_CHUNK; i++) {
        int idx = base + i;
        if (idx < N_NODES) { rowptr[idx] = run; run += deg[idx]; }
    }
    if (t == 0) rowptr[N_NODES] = part[SCAN_T - 1];
}

__global__ __launch_bounds__(256) void scatter_edges(
    const int* __restrict__ eidx, const int* __restrict__ rowptr,
    int* __restrict__ cursor, int* __restrict__ esrc)
{
    int e = blockIdx.x * blockDim.x + threadIdx.x;
    if (e >= E2) return;
    int src, dst;
    if (e < E_EDGES) { src = eidx[e]; dst = eidx[E_EDGES + e]; }
    else             { src = dst = e - E_EDGES; }
    int pos = atomicAdd(&cursor[dst], 1);
    esrc[rowptr[dst] + pos] = src;
}

// ------- MFMA GEMM + fused S/D: C = A@BT^T (+brow); S/D from f32 acc ---
// BROW: bias row = fixed-order sum of browp[0..31][col] (deterministic).
template<int K, bool BROW>
__global__ __launch_bounds__(256) void gemm_sd(
    const unsigned short* __restrict__ A, const unsigned short* __restrict__ BT,
    const float* __restrict__ browp, const float* __restrict__ a_src,
    const float* __restrict__ a_dst, unsigned short* __restrict__ C,
    float* __restrict__ S, float* __restrict__ D)
{
    const int t = threadIdx.x;
    const int wave = t >> 6, lane = t & 63;
    const int lo = lane & 15, hi = lane >> 4;
    const int row0 = blockIdx.x * 64;
    const int nbase = wave * 64;

    int arow[4];
#pragma unroll
    for (int m = 0; m < 4; m++)
        arow[m] = min(row0 + m * 16 + lo, N_NODES - 1);   // never read unwritten ws

    f32x4 acc[4][4];
#pragma unroll
    for (int m = 0; m < 4; m++)
#pragma unroll
        for (int n = 0; n < 4; n++)
            acc[m][n] = (f32x4){0.f, 0.f, 0.f, 0.f};

    for (int k0 = 0; k0 < K; k0 += 32) {
        const int kk = k0 + hi * 8;
        short8 af[4], bfr[4];
#pragma unroll
        for (int m = 0; m < 4; m++)
            af[m] = *reinterpret_cast<const short8*>(A + (size_t)arow[m] * K + kk);
#pragma unroll
        for (int n = 0; n < 4; n++)
            bfr[n] = *reinterpret_cast<const short8*>(BT + (size_t)(nbase + n * 16 + lo) * K + kk);
#pragma unroll
        for (int m = 0; m < 4; m++)
#pragma unroll
            for (int n = 0; n < 4; n++)
                acc[m][n] = __builtin_amdgcn_mfma_f32_16x16x32_bf16(
                    af[m], bfr[n], acc[m][n], 0, 0, 0);
    }

    float bb[4], asv[4], adv[4];
#pragma unroll
    for (int n = 0; n < 4; n++) {
        int col = nbase + n * 16 + lo;
        float bbv = 0.f;
        if (BROW)
            for (int b = 0; b < 32; b++)       // fixed order -> deterministic
                bbv += browp[b * F + col];
        bb[n]  = bbv;
        asv[n] = a_src[col];
        adv[n] = a_dst[col];
    }

#pragma unroll
    for (int m = 0; m < 4; m++) {
#pragma unroll
        for (int i = 0; i < 4; i++) {
            const int row = row0 + m * 16 + hi * 4 + i;
            const bool ok = row < N_NODES;
            float ps = 0.f, pd = 0.f;
#pragma unroll
            for (int n = 0; n < 4; n++) {
                float v = acc[m][n][i] + bb[n];
                ps += v * asv[n];
                pd += v * adv[n];
                if (ok) C[(size_t)row * F + nbase + n * 16 + lo] = f2bf(v);
            }
#pragma unroll
            for (int off = 1; off < 16; off <<= 1) {
                ps += __shfl_xor(ps, off, 64);
                pd += __shfl_xor(pd, off, 64);
            }
            if (lo == 0 && ok) {
                S[row * HEADS + wave] = ps;
                D[row * HEADS + wave] = pd;
            }
        }
    }
}

// ------- fused softmax + aggregation + bias + ReLU + sliced stats ------
// R6 inner loop (113.8us) + R10 sliced-atomic stats epilogue (proven).
__global__ __launch_bounds__(256) void gat_aggregate(
    const int* __restrict__ rowptr, const int* __restrict__ esrc,
    const float* __restrict__ S, const float* __restrict__ D,
    const unsigned short* __restrict__ XWb, const float* __restrict__ bias,
    unsigned short* __restrict__ Hb, float* __restrict__ stp)
{
    __shared__ int   sbuf[4][64];
    __shared__ float wbuf[4][64][4];
    __shared__ float red_s[4][F];
    __shared__ float red_q[4][F];
    const int wv   = threadIdx.x >> 6;
    const int lane = threadIdx.x & 63;
    const int dst  = blockIdx.x * 4 + wv;        // always < N_NODES (N%4==0)
    const int beg = rowptr[dst], end = rowptr[dst + 1];
    const int h = lane >> 4;
    const float4 d4 = *reinterpret_cast<const float4*>(D + dst * HEADS);

    float ax = 0.f, ay = 0.f, az = 0.f, aw = 0.f, den = 0.f;

    for (int i = beg; i < end; i += 64) {
        const int nb = min(64, end - i);
        const bool valid = (i + lane < end);
        const int mysrc = valid ? esrc[i + lane] : 0;   // row 0 always valid
        float4 w4 = {0.f, 0.f, 0.f, 0.f};
        if (valid) {
            const float4 s4 = *reinterpret_cast<const float4*>(S + mysrc * HEADS);
            float z;
            z = s4.x + d4.x; w4.x = __expf(z > 0.f ? z : NEG_SLOPE * z);
            z = s4.y + d4.y; w4.y = __expf(z > 0.f ? z : NEG_SLOPE * z);
            z = s4.z + d4.z; w4.z = __expf(z > 0.f ? z : NEG_SLOPE * z);
            z = s4.w + d4.w; w4.w = __expf(z > 0.f ? z : NEG_SLOPE * z);
        }
        sbuf[wv][lane] = mysrc;
        *reinterpret_cast<float4*>(&wbuf[wv][lane][0]) = w4;

        int j = 0;
        for (; j + 7 < nb; j += 8) {
            int s0 = sbuf[wv][j + 0], s1 = sbuf[wv][j + 1];
            int s2 = sbuf[wv][j + 2], s3 = sbuf[wv][j + 3];
            int s4i = sbuf[wv][j + 4], s5 = sbuf[wv][j + 5];
            int s6 = sbuf[wv][j + 6], s7 = sbuf[wv][j + 7];
            float w0 = wbuf[wv][j + 0][h], w1 = wbuf[wv][j + 1][h];
            float w2 = wbuf[wv][j + 2][h], w3 = wbuf[wv][j + 3][h];
            float w4f = wbuf[wv][j + 4][h], w5 = wbuf[wv][j + 5][h];
            float w6 = wbuf[wv][j + 6][h], w7 = wbuf[wv][j + 7][h];
            ushort4 x0 = *reinterpret_cast<const ushort4*>(XWb + (size_t)s0 * F + lane * 4);
            ushort4 x1 = *reinterpret_cast<const ushort4*>(XWb + (size_t)s1 * F + lane * 4);
            ushort4 x2 = *reinterpret_cast<const ushort4*>(XWb + (size_t)s2 * F + lane * 4);
            ushort4 x3 = *reinterpret_cast<const ushort4*>(XWb + (size_t)s3 * F + lane * 4);
            ushort4 x4 = *reinterpret_cast<const ushort4*>(XWb + (size_t)s4i * F + lane * 4);
            ushort4 x5 = *reinterpret_cast<const ushort4*>(XWb + (size_t)s5 * F + lane * 4);
            ushort4 x6 = *reinterpret_cast<const ushort4*>(XWb + (size_t)s6 * F + lane * 4);
            ushort4 x7 = *reinterpret_cast<const ushort4*>(XWb + (size_t)s7 * F + lane * 4);
            ax += w0 * bf2f(x0.x) + w1 * bf2f(x1.x) + w2 * bf2f(x2.x) + w3 * bf2f(x3.x)
                + w4f * bf2f(x4.x) + w5 * bf2f(x5.x) + w6 * bf2f(x6.x) + w7 * bf2f(x7.x);
            ay += w0 * bf2f(x0.y) + w1 * bf2f(x1.y) + w2 * bf2f(x2.y) + w3 * bf2f(x3.y)
                + w4f * bf2f(x4.y) + w5 * bf2f(x5.y) + w6 * bf2f(x6.y) + w7 * bf2f(x7.y);
            az += w0 * bf2f(x0.z) + w1 * bf2f(x1.z) + w2 * bf2f(x2.z) + w3 * bf2f(x3.z)
                + w4f * bf2f(x4.z) + w5 * bf2f(x5.z) + w6 * bf2f(x6.z) + w7 * bf2f(x7.z);
            aw += w0 * bf2f(x0.w) + w1 * bf2f(x1.w) + w2 * bf2f(x2.w) + w3 * bf2f(x3.w)
                + w4f * bf2f(x4.w) + w5 * bf2f(x5.w) + w6 * bf2f(x6.w) + w7 * bf2f(x7.w);
            den += ((w0 + w1) + (w2 + w3)) + ((w4f + w5) + (w6 + w7));
        }
        for (; j < nb; j++) {
            int   src = sbuf[wv][j];
            float w = wbuf[wv][j][h];
            ushort4 xv = *reinterpret_cast<const ushort4*>(XWb + (size_t)src * F + lane * 4);
            ax += w * bf2f(xv.x); ay += w * bf2f(xv.y);
            az += w * bf2f(xv.z); aw += w * bf2f(xv.w);
            den += w;
        }
    }

    const float inv = 1.f / (den + 1e-16f);
    float4 bv = *reinterpret_cast<const float4*>(bias + lane * 4);
    float v0 = ax * inv + bv.x, v1 = ay * inv + bv.y;
    float v2 = az * inv + bv.z, v3 = aw * inv + bv.w;
    v0 = v0 > 0.f ? v0 : 0.f; v1 = v1 > 0.f ? v1 : 0.f;
    v2 = v2 > 0.f ? v2 : 0.f; v3 = v3 > 0.f ? v3 : 0.f;
    ushort4 o = { f2bf(v0), f2bf(v1), f2bf(v2), f2bf(v3) };
    *reinterpret_cast<ushort4*>(Hb + (size_t)dst * F + lane * 4) = o;

    f32x4 rs = {v0, v1, v2, v3};
    f32x4 rq = {v0 * v0, v1 * v1, v2 * v2, v3 * v3};
    *reinterpret_cast<f32x4*>(&red_s[wv][lane * 4]) = rs;
    *reinterpret_cast<f32x4*>(&red_q[wv][lane * 4]) = rq;
    __syncthreads();
    // block stats -> SLICED atomics (spread contention NSLICE-ways)
    const int ch = threadIdx.x;
    float s = (red_s[0][ch] + red_s[1][ch]) + (red_s[2][ch] + red_s[3][ch]);
    float q = (red_q[0][ch] + red_q[1][ch]) + (red_q[2][ch] + red_q[3][ch]);
    float* slice = stp + (size_t)(blockIdx.x & (NSLICE - 1)) * (2 * F);
    atomicAdd(&slice[ch], s);
    atomicAdd(&slice[F + ch], q);
}

// ---- fold BN1 into W2 + brow partials; BN prep recomputed per block ---
// All 32 blocks derive identical sc/sh from stp (fixed-order slice sum).
__global__ __launch_bounds__(256) void fold_w2b(
    const float* __restrict__ stp, const float* __restrict__ g,
    const float* __restrict__ be, const float* __restrict__ W2,
    unsigned short* __restrict__ WT2b, float* __restrict__ browp)
{
    __shared__ float sc_l[F], sh_l[F];
    const int t = threadIdx.x;
    float s = 0.f, q = 0.f;
    for (int b = 0; b < NSLICE; b++) {       // fixed order
        s += stp[(size_t)b * 2 * F + t];
        q += stp[(size_t)b * 2 * F + F + t];
    }
    const float inv_n = 1.f / (float)N_NODES;
    float mu = s * inv_n;
    float var = q * inv_n - mu * mu;
    float sc = rsqrtf(var + BN_EPS) * g[t];
    sc_l[t] = sc;
    sh_l[t] = be[t] - mu * sc;
    __syncthreads();
    const int k0 = blockIdx.x * 8;
    float bacc = 0.f;
#pragma unroll
    for (int kk = 0; kk < 8; kk++) {
        float w = W2[(size_t)(k0 + kk) * F + t];
        WT2b[(size_t)t * F + k0 + kk] = f2bf(w * sc_l[k0 + kk]);
        bacc += sh_l[k0 + kk] * w;
    }
    browp[blockIdx.x * F + t] = bacc;
}

// ---------------- BN2 prep + fold into classifier weights, 1 block ----
__global__ __launch_bounds__(256) void fold_wc(
    const float* __restrict__ stp, const float* __restrict__ g,
    const float* __restrict__ be, const float* __restrict__ Wc,
    const float* __restrict__ bc, float* __restrict__ Wcp, float* __restrict__ bcp)
{
    __shared__ float sc_l[F], sh_l[F];
    const int t = threadIdx.x;
    float s = 0.f, q = 0.f;
    for (int b = 0; b < NSLICE; b++) {       // fixed order
        s += stp[(size_t)b * 2 * F + t];
        q += stp[(size_t)b * 2 * F + F + t];
    }
    const float inv_n = 1.f / (float)N_NODES;
    float mu = s * inv_n;
    float var = q * inv_n - mu * mu;
    float sc = rsqrtf(var + BN_EPS) * g[t];
    sc_l[t] = sc;
    sh_l[t] = be[t] - mu * sc;
    __syncthreads();
#pragma unroll
    for (int o = 0; o < OUTC; o++)
        Wcp[t * OUTC + o] = Wc[t * OUTC + o] * sc_l[t];
    if (t < OUTC) {
        float acc = bc[t];
        for (int kk = 0; kk < F; kk++)
            acc += sh_l[kk] * Wc[kk * OUTC + t];
        bcp[t] = acc;
    }
}

// ---------------- classifier: [N,256]bf16 @ Wcp[256,10] + bcp --------
__global__ __launch_bounds__(256) void classifier(
    const unsigned short* __restrict__ Hb, const float* __restrict__ Wcp,
    const float* __restrict__ bcp, float* __restrict__ out)
{
    __shared__ float wls[F][OUTC + 1];
    const int t = threadIdx.x;
    for (int i = t; i < F * OUTC; i += 256)
        wls[i / OUTC][i % OUTC] = Wcp[i];
    __syncthreads();

    const int wave = t >> 6, lane = t & 63;
    const int n = blockIdx.x * 4 + wave;
    if (n >= N_NODES) return;

    float v[4];
#pragma unroll
    for (int j = 0; j < 4; j++)
        v[j] = bf2f(Hb[(size_t)n * F + j * 64 + lane]);

    float acc[OUTC];
#pragma unroll
    for (int o = 0; o < OUTC; o++) acc[o] = 0.f;
#pragma unroll
    for (int j = 0; j < 4; j++)
#pragma unroll
        for (int o = 0; o < OUTC; o++)
            acc[o] += v[j] * wls[j * 64 + lane][o];

#pragma unroll
    for (int off = 32; off > 0; off >>= 1)
#pragma unroll
        for (int o = 0; o < OUTC; o++)
            acc[o] += __shfl_xor(acc[o], off, 64);

    if (lane == 0) {
#pragma unroll
        for (int o = 0; o < OUTC; o++)
            out[(size_t)n * OUTC + o] = acc[o] + bcp[o];
    }
}

extern "C" void kernel_launch(void* const* d_in, const int* in_sizes, int n_in,
                              void* d_out, int out_size, void* d_ws, size_t ws_size,
                              hipStream_t stream)
{
    const float* x   = (const float*)d_in[0];
    const int*   ei  = (const int*)d_in[1];
    const float* W1  = (const float*)d_in[2];
    const float* as1 = (const float*)d_in[3];
    const float* ad1 = (const float*)d_in[4];
    const float* b1  = (const float*)d_in[5];
    const float* W2  = (const float*)d_in[6];
    const float* as2 = (const float*)d_in[7];
    const float* ad2 = (const float*)d_in[8];
    const float* b2  = (const float*)d_in[9];
    const float* g1  = (const float*)d_in[10];
    const float* be1 = (const float*)d_in[11];
    const float* g2  = (const float*)d_in[12];
    const float* be2 = (const float*)d_in[13];
    const float* Wc  = (const float*)d_in[14];
    const float* bc  = (const float*)d_in[15];
    float* out = (float*)d_out;

    char* w = (char*)d_ws;
    // zero-init region first (one memset): deg | cursor | stp1 | stp2
    int*   deg   = (int*)w;                      w += (size_t)N_NODES * 4;
    int*   cursor= (int*)w;                      w += (size_t)N_NODES * 4;
    float* stp1  = (float*)w;                    w += (size_t)NSLICE * 2 * F * 4;
    float* stp2  = (float*)w;                    w += (size_t)NSLICE * 2 * F * 4;
    const size_t zero_bytes = (size_t)N_NODES * 8 + (size_t)NSLICE * 2 * F * 8;

    unsigned short* Xb   = (unsigned short*)w;   w += (size_t)N_NODES * 128 * 2;
    unsigned short* XWb  = (unsigned short*)w;   w += (size_t)N_NODES * F * 2;
    unsigned short* Hb   = (unsigned short*)w;   w += (size_t)N_NODES * F * 2;
    unsigned short* WT1b = (unsigned short*)w;   w += 256 * 128 * 2;
    unsigned short* WT2b = (unsigned short*)w;   w += 256 * 256 * 2;
    float* Wcp   = (float*)w;                    w += F * OUTC * 4;
    float* bcp   = (float*)w;                    w += 64;
    float* browp = (float*)w;                    w += 32 * F * 4;
    float* Sv    = (float*)w;                    w += (size_t)N_NODES * HEADS * 4;
    float* Dv    = (float*)w;                    w += (size_t)N_NODES * HEADS * 4;
    int* rowp    = (int*)w;                      w += (size_t)(N_NODES + 1) * 4;
    int* esrc    = (int*)w;                      /* E2 ints */

    const int grid_e    = (E2 + 255) / 256;
    const int grid_nw   = N_NODES / 4;           // 12500, exact
    const int grid_gemm = (N_NODES + 63) / 64;   // 782
    const int grid_prep = CXB + CWB + CDB;       // 12824

    // ---- prep (3 dispatches) ----
    hipMemsetAsync(deg, 0, zero_bytes, stream);
    mega_prep<<<grid_prep, 256, 0, stream>>>(x, Xb, W1, WT1b, ei, deg);
    scan_deg<<<1, SCAN_T, 0, stream>>>(deg, rowp);
    scatter_edges<<<grid_e, 256, 0, stream>>>(ei, rowp, cursor, esrc);

    // ---- layer 1 ----
    gemm_sd<128, false><<<grid_gemm, 256, 0, stream>>>(
        Xb, WT1b, nullptr, as1, ad1, XWb, Sv, Dv);
    gat_aggregate<<<grid_nw, 256, 0, stream>>>(rowp, esrc, Sv, Dv, XWb, b1, Hb, stp1);
    fold_w2b<<<32, 256, 0, stream>>>(stp1, g1, be1, W2, WT2b, browp);

    // ---- layer 2 ----
    gemm_sd<256, true><<<grid_gemm, 256, 0, stream>>>(
        Hb, WT2b, browp, as2, ad2, XWb, Sv, Dv);
    gat_aggregate<<<grid_nw, 256, 0, stream>>>(rowp, esrc, Sv, Dv, XWb, b2, Hb, stp2);
    fold_wc<<<1, 256, 0, stream>>>(stp2, g2, be2, Wc, bc, Wcp, bcp);

    // ---- classifier ----
    classifier<<<grid_nw, 256, 0, stream>>>(Hb, Wcp, bcp, out);
}

// Round 12
// 568.984 us; speedup vs baseline: 1.1296x; 1.1296x over previous
//
#include <hip/hip_runtime.h>

#define N_NODES 50000
#define E_EDGES 1600000
#define E2 (E_EDGES + N_NODES)   // 1,650,000 with self loops
#define HEADS 4
#define F 256
#define OUTC 10
#define BN_EPS 1e-5f
#define NEG_SLOPE 0.2f
#define NSLICE 64                // stats atomic-spreading slices
#define SB 1024                  // scan block size
#define NB ((N_NODES + SB - 1) / SB)   // 49 scan blocks

// mega_prep block ranges
#define CXB (N_NODES * 128 / 4 / 256)        // 6250 convert_x blocks
#define CWB 128                               // convert_w1T blocks
#define CDB ((E2 + 255) / 256)                // 6446 count_deg blocks

static_assert(N_NODES % 4 == 0, "grid_nw exact");

typedef __attribute__((ext_vector_type(8))) short short8;
typedef __attribute__((ext_vector_type(4))) float f32x4;

__device__ __forceinline__ unsigned short f2bf(float f) {
    unsigned int u = __float_as_uint(f);
    unsigned int r = (u + 0x7fffu + ((u >> 16) & 1u)) >> 16;
    return (unsigned short)r;
}
__device__ __forceinline__ float bf2f(unsigned short b) {
    return __uint_as_float(((unsigned int)b) << 16);
}

// ---- fused prep: convert_x | convert_w1T | count_deg (branch on block) --
__global__ __launch_bounds__(256) void mega_prep(
    const float* __restrict__ X, unsigned short* __restrict__ Xb,
    const float* __restrict__ W1, unsigned short* __restrict__ WT,
    const int* __restrict__ eidx, int* __restrict__ deg)
{
    const int b = blockIdx.x;
    const int t = threadIdx.x;
    if (b < CXB) {
        const int i = b * 256 + t;                 // float4 index, exact
        float4 v = reinterpret_cast<const float4*>(X)[i];
        ushort4 o = { f2bf(v.x), f2bf(v.y), f2bf(v.z), f2bf(v.w) };
        reinterpret_cast<ushort4*>(Xb)[i] = o;
    } else if (b < CXB + CWB) {
        const int k = b - CXB;                     // W1 row
        WT[t * 128 + k] = f2bf(W1[k * 256 + t]);
    } else {
        const int e = (b - CXB - CWB) * 256 + t;
        if (e < E2) {
            int dst = (e < E_EDGES) ? eidx[E_EDGES + e] : e - E_EDGES;
            atomicAdd(&deg[dst], 1);
        }
    }
}

// ---- parallel scan, 2 dispatches (R10-proven structure) ----
__global__ __launch_bounds__(SB) void scan_blocks(
    const int* __restrict__ deg, int* __restrict__ rowptr, int* __restrict__ bsum)
{
    __shared__ int sm[SB];
    const int t = threadIdx.x;
    const int idx = blockIdx.x * SB + t;
    int v = (idx < N_NODES) ? deg[idx] : 0;
    sm[t] = v;
    __syncthreads();
    for (int off = 1; off < SB; off <<= 1) {
        int u = (t >= off) ? sm[t - off] : 0;
        __syncthreads();
        sm[t] += u;
        __syncthreads();
    }
    if (idx < N_NODES) rowptr[idx] = sm[t] - v;   // exclusive within block
    if (t == SB - 1) bsum[blockIdx.x] = sm[t];
}

// each block redundantly computes its prefix of bsum (fixed order, <=49 adds)
__global__ __launch_bounds__(SB) void scan_add2(
    int* __restrict__ rowptr, const int* __restrict__ bsum)
{
    __shared__ int boff_s;
    if (threadIdx.x == 0) {
        int run = 0;
        for (int b = 0; b < (int)blockIdx.x; b++) run += bsum[b];
        boff_s = run;
        if (blockIdx.x == 0) {
            int tot = 0;
            for (int b = 0; b < NB; b++) tot += bsum[b];
            rowptr[N_NODES] = tot;
        }
    }
    __syncthreads();
    const int idx = blockIdx.x * SB + threadIdx.x;
    if (idx < N_NODES) rowptr[idx] += boff_s;
}

__global__ __launch_bounds__(256) void scatter_edges(
    const int* __restrict__ eidx, const int* __restrict__ rowptr,
    int* __restrict__ cursor, int* __restrict__ esrc)
{
    int e = blockIdx.x * blockDim.x + threadIdx.x;
    if (e >= E2) return;
    int src, dst;
    if (e < E_EDGES) { src = eidx[e]; dst = eidx[E_EDGES + e]; }
    else             { src = dst = e - E_EDGES; }
    int pos = atomicAdd(&cursor[dst], 1);
    esrc[rowptr[dst] + pos] = src;
}

// ------- MFMA GEMM + fused S/D: C = A@BT^T (+brow); S/D from f32 acc ---
// BROW: bias row = fixed-order sum of browp[0..31][col] (deterministic).
template<int K, bool BROW>
__global__ __launch_bounds__(256) void gemm_sd(
    const unsigned short* __restrict__ A, const unsigned short* __restrict__ BT,
    const float* __restrict__ browp, const float* __restrict__ a_src,
    const float* __restrict__ a_dst, unsigned short* __restrict__ C,
    float* __restrict__ S, float* __restrict__ D)
{
    const int t = threadIdx.x;
    const int wave = t >> 6, lane = t & 63;
    const int lo = lane & 15, hi = lane >> 4;
    const int row0 = blockIdx.x * 64;
    const int nbase = wave * 64;

    int arow[4];
#pragma unroll
    for (int m = 0; m < 4; m++)
        arow[m] = min(row0 + m * 16 + lo, N_NODES - 1);   // never read unwritten ws

    f32x4 acc[4][4];
#pragma unroll
    for (int m = 0; m < 4; m++)
#pragma unroll
        for (int n = 0; n < 4; n++)
            acc[m][n] = (f32x4){0.f, 0.f, 0.f, 0.f};

    for (int k0 = 0; k0 < K; k0 += 32) {
        const int kk = k0 + hi * 8;
        short8 af[4], bfr[4];
#pragma unroll
        for (int m = 0; m < 4; m++)
            af[m] = *reinterpret_cast<const short8*>(A + (size_t)arow[m] * K + kk);
#pragma unroll
        for (int n = 0; n < 4; n++)
            bfr[n] = *reinterpret_cast<const short8*>(BT + (size_t)(nbase + n * 16 + lo) * K + kk);
#pragma unroll
        for (int m = 0; m < 4; m++)
#pragma unroll
            for (int n = 0; n < 4; n++)
                acc[m][n] = __builtin_amdgcn_mfma_f32_16x16x32_bf16(
                    af[m], bfr[n], acc[m][n], 0, 0, 0);
    }

    float bb[4], asv[4], adv[4];
#pragma unroll
    for (int n = 0; n < 4; n++) {
        int col = nbase + n * 16 + lo;
        float bbv = 0.f;
        if (BROW)
            for (int b = 0; b < 32; b++)       // fixed order -> deterministic
                bbv += browp[b * F + col];
        bb[n]  = bbv;
        asv[n] = a_src[col];
        adv[n] = a_dst[col];
    }

#pragma unroll
    for (int m = 0; m < 4; m++) {
#pragma unroll
        for (int i = 0; i < 4; i++) {
            const int row = row0 + m * 16 + hi * 4 + i;
            const bool ok = row < N_NODES;
            float ps = 0.f, pd = 0.f;
#pragma unroll
            for (int n = 0; n < 4; n++) {
                float v = acc[m][n][i] + bb[n];
                ps += v * asv[n];
                pd += v * adv[n];
                if (ok) C[(size_t)row * F + nbase + n * 16 + lo] = f2bf(v);
            }
#pragma unroll
            for (int off = 1; off < 16; off <<= 1) {
                ps += __shfl_xor(ps, off, 64);
                pd += __shfl_xor(pd, off, 64);
            }
            if (lo == 0 && ok) {
                S[row * HEADS + wave] = ps;
                D[row * HEADS + wave] = pd;
            }
        }
    }
}

// ------- fused softmax + aggregation + bias + ReLU + sliced stats ------
// R6 inner loop (113.8us) + R10 sliced-atomic stats epilogue (proven).
__global__ __launch_bounds__(256) void gat_aggregate(
    const int* __restrict__ rowptr, const int* __restrict__ esrc,
    const float* __restrict__ S, const float* __restrict__ D,
    const unsigned short* __restrict__ XWb, const float* __restrict__ bias,
    unsigned short* __restrict__ Hb, float* __restrict__ stp)
{
    __shared__ int   sbuf[4][64];
    __shared__ float wbuf[4][64][4];
    __shared__ float red_s[4][F];
    __shared__ float red_q[4][F];
    const int wv   = threadIdx.x >> 6;
    const int lane = threadIdx.x & 63;
    const int dst  = blockIdx.x * 4 + wv;        // always < N_NODES (N%4==0)
    const int beg = rowptr[dst], end = rowptr[dst + 1];
    const int h = lane >> 4;
    const float4 d4 = *reinterpret_cast<const float4*>(D + dst * HEADS);

    float ax = 0.f, ay = 0.f, az = 0.f, aw = 0.f, den = 0.f;

    for (int i = beg; i < end; i += 64) {
        const int nb = min(64, end - i);
        const bool valid = (i + lane < end);
        const int mysrc = valid ? esrc[i + lane] : 0;   // row 0 always valid
        float4 w4 = {0.f, 0.f, 0.f, 0.f};
        if (valid) {
            const float4 s4 = *reinterpret_cast<const float4*>(S + mysrc * HEADS);
            float z;
            z = s4.x + d4.x; w4.x = __expf(z > 0.f ? z : NEG_SLOPE * z);
            z = s4.y + d4.y; w4.y = __expf(z > 0.f ? z : NEG_SLOPE * z);
            z = s4.z + d4.z; w4.z = __expf(z > 0.f ? z : NEG_SLOPE * z);
            z = s4.w + d4.w; w4.w = __expf(z > 0.f ? z : NEG_SLOPE * z);
        }
        sbuf[wv][lane] = mysrc;
        *reinterpret_cast<float4*>(&wbuf[wv][lane][0]) = w4;

        int j = 0;
        for (; j + 7 < nb; j += 8) {
            int s0 = sbuf[wv][j + 0], s1 = sbuf[wv][j + 1];
            int s2 = sbuf[wv][j + 2], s3 = sbuf[wv][j + 3];
            int s4i = sbuf[wv][j + 4], s5 = sbuf[wv][j + 5];
            int s6 = sbuf[wv][j + 6], s7 = sbuf[wv][j + 7];
            float w0 = wbuf[wv][j + 0][h], w1 = wbuf[wv][j + 1][h];
            float w2 = wbuf[wv][j + 2][h], w3 = wbuf[wv][j + 3][h];
            float w4f = wbuf[wv][j + 4][h], w5 = wbuf[wv][j + 5][h];
            float w6 = wbuf[wv][j + 6][h], w7 = wbuf[wv][j + 7][h];
            ushort4 x0 = *reinterpret_cast<const ushort4*>(XWb + (size_t)s0 * F + lane * 4);
            ushort4 x1 = *reinterpret_cast<const ushort4*>(XWb + (size_t)s1 * F + lane * 4);
            ushort4 x2 = *reinterpret_cast<const ushort4*>(XWb + (size_t)s2 * F + lane * 4);
            ushort4 x3 = *reinterpret_cast<const ushort4*>(XWb + (size_t)s3 * F + lane * 4);
            ushort4 x4 = *reinterpret_cast<const ushort4*>(XWb + (size_t)s4i * F + lane * 4);
            ushort4 x5 = *reinterpret_cast<const ushort4*>(XWb + (size_t)s5 * F + lane * 4);
            ushort4 x6 = *reinterpret_cast<const ushort4*>(XWb + (size_t)s6 * F + lane * 4);
            ushort4 x7 = *reinterpret_cast<const ushort4*>(XWb + (size_t)s7 * F + lane * 4);
            ax += w0 * bf2f(x0.x) + w1 * bf2f(x1.x) + w2 * bf2f(x2.x) + w3 * bf2f(x3.x)
                + w4f * bf2f(x4.x) + w5 * bf2f(x5.x) + w6 * bf2f(x6.x) + w7 * bf2f(x7.x);
            ay += w0 * bf2f(x0.y) + w1 * bf2f(x1.y) + w2 * bf2f(x2.y) + w3 * bf2f(x3.y)
                + w4f * bf2f(x4.y) + w5 * bf2f(x5.y) + w6 * bf2f(x6.y) + w7 * bf2f(x7.y);
            az += w0 * bf2f(x0.z) + w1 * bf2f(x1.z) + w2 * bf2f(x2.z) + w3 * bf2f(x3.z)
                + w4f * bf2f(x4.z) + w5 * bf2f(x5.z) + w6 * bf2f(x6.z) + w7 * bf2f(x7.z);
            aw += w0 * bf2f(x0.w) + w1 * bf2f(x1.w) + w2 * bf2f(x2.w) + w3 * bf2f(x3.w)
                + w4f * bf2f(x4.w) + w5 * bf2f(x5.w) + w6 * bf2f(x6.w) + w7 * bf2f(x7.w);
            den += ((w0 + w1) + (w2 + w3)) + ((w4f + w5) + (w6 + w7));
        }
        for (; j < nb; j++) {
            int   src = sbuf[wv][j];
            float w = wbuf[wv][j][h];
            ushort4 xv = *reinterpret_cast<const ushort4*>(XWb + (size_t)src * F + lane * 4);
            ax += w * bf2f(xv.x); ay += w * bf2f(xv.y);
            az += w * bf2f(xv.z); aw += w * bf2f(xv.w);
            den += w;
        }
    }

    const float inv = 1.f / (den + 1e-16f);
    float4 bv = *reinterpret_cast<const float4*>(bias + lane * 4);
    float v0 = ax * inv + bv.x, v1 = ay * inv + bv.y;
    float v2 = az * inv + bv.z, v3 = aw * inv + bv.w;
    v0 = v0 > 0.f ? v0 : 0.f; v1 = v1 > 0.f ? v1 : 0.f;
    v2 = v2 > 0.f ? v2 : 0.f; v3 = v3 > 0.f ? v3 : 0.f;
    ushort4 o = { f2bf(v0), f2bf(v1), f2bf(v2), f2bf(v3) };
    *reinterpret_cast<ushort4*>(Hb + (size_t)dst * F + lane * 4) = o;

    f32x4 rs = {v0, v1, v2, v3};
    f32x4 rq = {v0 * v0, v1 * v1, v2 * v2, v3 * v3};
    *reinterpret_cast<f32x4*>(&red_s[wv][lane * 4]) = rs;
    *reinterpret_cast<f32x4*>(&red_q[wv][lane * 4]) = rq;
    __syncthreads();
    // block stats -> SLICED atomics (spread contention NSLICE-ways)
    const int ch = threadIdx.x;
    float s = (red_s[0][ch] + red_s[1][ch]) + (red_s[2][ch] + red_s[3][ch]);
    float q = (red_q[0][ch] + red_q[1][ch]) + (red_q[2][ch] + red_q[3][ch]);
    float* slice = stp + (size_t)(blockIdx.x & (NSLICE - 1)) * (2 * F);
    atomicAdd(&slice[ch], s);
    atomicAdd(&slice[F + ch], q);
}

// ---- fold BN1 into W2 + brow partials; BN prep recomputed per block ---
// All 32 blocks derive identical sc/sh from stp (fixed-order slice sum).
__global__ __launch_bounds__(256) void fold_w2b(
    const float* __restrict__ stp, const float* __restrict__ g,
    const float* __restrict__ be, const float* __restrict__ W2,
    unsigned short* __restrict__ WT2b, float* __restrict__ browp)
{
    __shared__ float sc_l[F], sh_l[F];
    const int t = threadIdx.x;
    float s = 0.f, q = 0.f;
    for (int b = 0; b < NSLICE; b++) {       // fixed order
        s += stp[(size_t)b * 2 * F + t];
        q += stp[(size_t)b * 2 * F + F + t];
    }
    const float inv_n = 1.f / (float)N_NODES;
    float mu = s * inv_n;
    float var = q * inv_n - mu * mu;
    float sc = rsqrtf(var + BN_EPS) * g[t];
    sc_l[t] = sc;
    sh_l[t] = be[t] - mu * sc;
    __syncthreads();
    const int k0 = blockIdx.x * 8;
    float bacc = 0.f;
#pragma unroll
    for (int kk = 0; kk < 8; kk++) {
        float w = W2[(size_t)(k0 + kk) * F + t];
        WT2b[(size_t)t * F + k0 + kk] = f2bf(w * sc_l[k0 + kk]);
        bacc += sh_l[k0 + kk] * w;
    }
    browp[blockIdx.x * F + t] = bacc;
}

// ---------------- BN2 prep + fold into classifier weights, 1 block ----
__global__ __launch_bounds__(256) void fold_wc(
    const float* __restrict__ stp, const float* __restrict__ g,
    const float* __restrict__ be, const float* __restrict__ Wc,
    const float* __restrict__ bc, float* __restrict__ Wcp, float* __restrict__ bcp)
{
    __shared__ float sc_l[F], sh_l[F];
    const int t = threadIdx.x;
    float s = 0.f, q = 0.f;
    for (int b = 0; b < NSLICE; b++) {       // fixed order
        s += stp[(size_t)b * 2 * F + t];
        q += stp[(size_t)b * 2 * F + F + t];
    }
    const float inv_n = 1.f / (float)N_NODES;
    float mu = s * inv_n;
    float var = q * inv_n - mu * mu;
    float sc = rsqrtf(var + BN_EPS) * g[t];
    sc_l[t] = sc;
    sh_l[t] = be[t] - mu * sc;
    __syncthreads();
#pragma unroll
    for (int o = 0; o < OUTC; o++)
        Wcp[t * OUTC + o] = Wc[t * OUTC + o] * sc_l[t];
    if (t < OUTC) {
        float acc = bc[t];
        for (int kk = 0; kk < F; kk++)
            acc += sh_l[kk] * Wc[kk * OUTC + t];
        bcp[t] = acc;
    }
}

// ---------------- classifier: [N,256]bf16 @ Wcp[256,10] + bcp --------
__global__ __launch_bounds__(256) void classifier(
    const unsigned short* __restrict__ Hb, const float* __restrict__ Wcp,
    const float* __restrict__ bcp, float* __restrict__ out)
{
    __shared__ float wls[F][OUTC + 1];
    const int t = threadIdx.x;
    for (int i = t; i < F * OUTC; i += 256)
        wls[i / OUTC][i % OUTC] = Wcp[i];
    __syncthreads();

    const int wave = t >> 6, lane = t & 63;
    const int n = blockIdx.x * 4 + wave;
    if (n >= N_NODES) return;

    float v[4];
#pragma unroll
    for (int j = 0; j < 4; j++)
        v[j] = bf2f(Hb[(size_t)n * F + j * 64 + lane]);

    float acc[OUTC];
#pragma unroll
    for (int o = 0; o < OUTC; o++) acc[o] = 0.f;
#pragma unroll
    for (int j = 0; j < 4; j++)
#pragma unroll
        for (int o = 0; o < OUTC; o++)
            acc[o] += v[j] * wls[j * 64 + lane][o];

#pragma unroll
    for (int off = 32; off > 0; off >>= 1)
#pragma unroll
        for (int o = 0; o < OUTC; o++)
            acc[o] += __shfl_xor(acc[o], off, 64);

    if (lane == 0) {
#pragma unroll
        for (int o = 0; o < OUTC; o++)
            out[(size_t)n * OUTC + o] = acc[o] + bcp[o];
    }
}

extern "C" void kernel_launch(void* const* d_in, const int* in_sizes, int n_in,
                              void* d_out, int out_size, void* d_ws, size_t ws_size,
                              hipStream_t stream)
{
    const float* x   = (const float*)d_in[0];
    const int*   ei  = (const int*)d_in[1];
    const float* W1  = (const float*)d_in[2];
    const float* as1 = (const float*)d_in[3];
    const float* ad1 = (const float*)d_in[4];
    const float* b1  = (const float*)d_in[5];
    const float* W2  = (const float*)d_in[6];
    const float* as2 = (const float*)d_in[7];
    const float* ad2 = (const float*)d_in[8];
    const float* b2  = (const float*)d_in[9];
    const float* g1  = (const float*)d_in[10];
    const float* be1 = (const float*)d_in[11];
    const float* g2  = (const float*)d_in[12];
    const float* be2 = (const float*)d_in[13];
    const float* Wc  = (const float*)d_in[14];
    const float* bc  = (const float*)d_in[15];
    float* out = (float*)d_out;

    char* w = (char*)d_ws;
    // zero-init region first (one memset): deg | cursor | stp1 | stp2
    int*   deg   = (int*)w;                      w += (size_t)N_NODES * 4;
    int*   cursor= (int*)w;                      w += (size_t)N_NODES * 4;
    float* stp1  = (float*)w;                    w += (size_t)NSLICE * 2 * F * 4;
    float* stp2  = (float*)w;                    w += (size_t)NSLICE * 2 * F * 4;
    const size_t zero_bytes = (size_t)N_NODES * 8 + (size_t)NSLICE * 2 * F * 8;

    unsigned short* Xb   = (unsigned short*)w;   w += (size_t)N_NODES * 128 * 2;
    unsigned short* XWb  = (unsigned short*)w;   w += (size_t)N_NODES * F * 2;
    unsigned short* Hb   = (unsigned short*)w;   w += (size_t)N_NODES * F * 2;
    unsigned short* WT1b = (unsigned short*)w;   w += 256 * 128 * 2;
    unsigned short* WT2b = (unsigned short*)w;   w += 256 * 256 * 2;
    float* Wcp   = (float*)w;                    w += F * OUTC * 4;
    float* bcp   = (float*)w;                    w += 64;
    float* browp = (float*)w;                    w += 32 * F * 4;
    float* Sv    = (float*)w;                    w += (size_t)N_NODES * HEADS * 4;
    float* Dv    = (float*)w;                    w += (size_t)N_NODES * HEADS * 4;
    int* rowp    = (int*)w;                      w += (size_t)(N_NODES + 1) * 4;
    int* bsum    = (int*)w;                      w += NB * 4;
    int* esrc    = (int*)w;                      /* E2 ints */

    const int grid_e    = (E2 + 255) / 256;
    const int grid_nw   = N_NODES / 4;           // 12500, exact
    const int grid_gemm = (N_NODES + 63) / 64;   // 782
    const int grid_prep = CXB + CWB + CDB;       // 12824

    // ---- prep (4 dispatches + memset) ----
    hipMemsetAsync(deg, 0, zero_bytes, stream);
    mega_prep<<<grid_prep, 256, 0, stream>>>(x, Xb, W1, WT1b, ei, deg);
    scan_blocks<<<NB, SB, 0, stream>>>(deg, rowp, bsum);
    scan_add2<<<NB, SB, 0, stream>>>(rowp, bsum);
    scatter_edges<<<grid_e, 256, 0, stream>>>(ei, rowp, cursor, esrc);

    // ---- layer 1 ----
    gemm_sd<128, false><<<grid_gemm, 256, 0, stream>>>(
        Xb, WT1b, nullptr, as1, ad1, XWb, Sv, Dv);
    gat_aggregate<<<grid_nw, 256, 0, stream>>>(rowp, esrc, Sv, Dv, XWb, b1, Hb, stp1);
    fold_w2b<<<32, 256, 0, stream>>>(stp1, g1, be1, W2, WT2b, browp);

    // ---- layer 2 ----
    gemm_sd<256, true><<<grid_gemm, 256, 0, stream>>>(
        Hb, WT2b, browp, as2, ad2, XWb, Sv, Dv);
    gat_aggregate<<<grid_nw, 256, 0, stream>>>(rowp, esrc, Sv, Dv, XWb, b2, Hb, stp2);
    fold_wc<<<1, 256, 0, stream>>>(stp2, g2, be2, Wc, bc, Wcp, bcp);

    // ---- classifier ----
    classifier<<<grid_nw, 256, 0, stream>>>(Hb, Wcp, bcp, out);
}

// Round 13
// 565.110 us; speedup vs baseline: 1.1374x; 1.0069x over previous
//
#include <hip/hip_runtime.h>

#define N_NODES 50000
#define E_EDGES 1600000
#define E2 (E_EDGES + N_NODES)   // 1,650,000 with self loops
#define HEADS 4
#define F 256
#define OUTC 10
#define BN_EPS 1e-5f
#define NEG_SLOPE 0.2f
#define NSLICE 64                // stats atomic-spreading slices
#define SB 1024                  // scan block size
#define NB ((N_NODES + SB - 1) / SB)   // 49 scan blocks

// mega_prep block ranges
#define CXB (N_NODES * 128 / 4 / 256)        // 6250 convert_x blocks
#define CWB 128                               // convert_w1T blocks
#define CDB ((E2 + 255) / 256)                // 6446 count_deg blocks

static_assert(N_NODES % 4 == 0, "grid_nw exact");

typedef __attribute__((ext_vector_type(8))) short short8;
typedef __attribute__((ext_vector_type(4))) float f32x4;

__device__ __forceinline__ unsigned short f2bf(float f) {
    unsigned int u = __float_as_uint(f);
    unsigned int r = (u + 0x7fffu + ((u >> 16) & 1u)) >> 16;
    return (unsigned short)r;
}
__device__ __forceinline__ float bf2f(unsigned short b) {
    return __uint_as_float(((unsigned int)b) << 16);
}

// ---- fused prep: convert_x | convert_w1T | count_deg (branch on block) --
__global__ __launch_bounds__(256) void mega_prep(
    const float* __restrict__ X, unsigned short* __restrict__ Xb,
    const float* __restrict__ W1, unsigned short* __restrict__ WT,
    const int* __restrict__ eidx, int* __restrict__ deg)
{
    const int b = blockIdx.x;
    const int t = threadIdx.x;
    if (b < CXB) {
        const int i = b * 256 + t;                 // float4 index, exact
        float4 v = reinterpret_cast<const float4*>(X)[i];
        ushort4 o = { f2bf(v.x), f2bf(v.y), f2bf(v.z), f2bf(v.w) };
        reinterpret_cast<ushort4*>(Xb)[i] = o;
    } else if (b < CXB + CWB) {
        const int k = b - CXB;                     // W1 row
        WT[t * 128 + k] = f2bf(W1[k * 256 + t]);
    } else {
        const int e = (b - CXB - CWB) * 256 + t;
        if (e < E2) {
            int dst = (e < E_EDGES) ? eidx[E_EDGES + e] : e - E_EDGES;
            atomicAdd(&deg[dst], 1);
        }
    }
}

// ---- parallel scan, 2 dispatches (R10/R12-proven) ----
__global__ __launch_bounds__(SB) void scan_blocks(
    const int* __restrict__ deg, int* __restrict__ rowptr, int* __restrict__ bsum)
{
    __shared__ int sm[SB];
    const int t = threadIdx.x;
    const int idx = blockIdx.x * SB + t;
    int v = (idx < N_NODES) ? deg[idx] : 0;
    sm[t] = v;
    __syncthreads();
    for (int off = 1; off < SB; off <<= 1) {
        int u = (t >= off) ? sm[t - off] : 0;
        __syncthreads();
        sm[t] += u;
        __syncthreads();
    }
    if (idx < N_NODES) rowptr[idx] = sm[t] - v;   // exclusive within block
    if (t == SB - 1) bsum[blockIdx.x] = sm[t];
}

// each block redundantly computes its prefix of bsum (fixed order, <=49 adds)
__global__ __launch_bounds__(SB) void scan_add2(
    int* __restrict__ rowptr, const int* __restrict__ bsum)
{
    __shared__ int boff_s;
    if (threadIdx.x == 0) {
        int run = 0;
        for (int b = 0; b < (int)blockIdx.x; b++) run += bsum[b];
        boff_s = run;
        if (blockIdx.x == 0) {
            int tot = 0;
            for (int b = 0; b < NB; b++) tot += bsum[b];
            rowptr[N_NODES] = tot;
        }
    }
    __syncthreads();
    const int idx = blockIdx.x * SB + threadIdx.x;
    if (idx < N_NODES) rowptr[idx] += boff_s;
}

__global__ __launch_bounds__(256) void scatter_edges(
    const int* __restrict__ eidx, const int* __restrict__ rowptr,
    int* __restrict__ cursor, int* __restrict__ esrc)
{
    int e = blockIdx.x * blockDim.x + threadIdx.x;
    if (e >= E2) return;
    int src, dst;
    if (e < E_EDGES) { src = eidx[e]; dst = eidx[E_EDGES + e]; }
    else             { src = dst = e - E_EDGES; }
    int pos = atomicAdd(&cursor[dst], 1);
    esrc[rowptr[dst] + pos] = src;
}

// ------- MFMA GEMM + fused S/D: C = A@BT^T (+brow); S/D from f32 acc ---
template<int K, bool BROW>
__global__ __launch_bounds__(256) void gemm_sd(
    const unsigned short* __restrict__ A, const unsigned short* __restrict__ BT,
    const float* __restrict__ brow, const float* __restrict__ a_src,
    const float* __restrict__ a_dst, unsigned short* __restrict__ C,
    float* __restrict__ S, float* __restrict__ D)
{
    const int t = threadIdx.x;
    const int wave = t >> 6, lane = t & 63;
    const int lo = lane & 15, hi = lane >> 4;
    const int row0 = blockIdx.x * 64;
    const int nbase = wave * 64;

    int arow[4];
#pragma unroll
    for (int m = 0; m < 4; m++)
        arow[m] = min(row0 + m * 16 + lo, N_NODES - 1);   // never read unwritten ws

    f32x4 acc[4][4];
#pragma unroll
    for (int m = 0; m < 4; m++)
#pragma unroll
        for (int n = 0; n < 4; n++)
            acc[m][n] = (f32x4){0.f, 0.f, 0.f, 0.f};

    for (int k0 = 0; k0 < K; k0 += 32) {
        const int kk = k0 + hi * 8;
        short8 af[4], bfr[4];
#pragma unroll
        for (int m = 0; m < 4; m++)
            af[m] = *reinterpret_cast<const short8*>(A + (size_t)arow[m] * K + kk);
#pragma unroll
        for (int n = 0; n < 4; n++)
            bfr[n] = *reinterpret_cast<const short8*>(BT + (size_t)(nbase + n * 16 + lo) * K + kk);
#pragma unroll
        for (int m = 0; m < 4; m++)
#pragma unroll
            for (int n = 0; n < 4; n++)
                acc[m][n] = __builtin_amdgcn_mfma_f32_16x16x32_bf16(
                    af[m], bfr[n], acc[m][n], 0, 0, 0);
    }

    float bb[4], asv[4], adv[4];
#pragma unroll
    for (int n = 0; n < 4; n++) {
        int col = nbase + n * 16 + lo;
        bb[n]  = BROW ? brow[col] : 0.f;
        asv[n] = a_src[col];
        adv[n] = a_dst[col];
    }

#pragma unroll
    for (int m = 0; m < 4; m++) {
#pragma unroll
        for (int i = 0; i < 4; i++) {
            const int row = row0 + m * 16 + hi * 4 + i;
            const bool ok = row < N_NODES;
            float ps = 0.f, pd = 0.f;
#pragma unroll
            for (int n = 0; n < 4; n++) {
                float v = acc[m][n][i] + bb[n];
                ps += v * asv[n];
                pd += v * adv[n];
                if (ok) C[(size_t)row * F + nbase + n * 16 + lo] = f2bf(v);
            }
#pragma unroll
            for (int off = 1; off < 16; off <<= 1) {
                ps += __shfl_xor(ps, off, 64);
                pd += __shfl_xor(pd, off, 64);
            }
            if (lo == 0 && ok) {
                S[row * HEADS + wave] = ps;
                D[row * HEADS + wave] = pd;
            }
        }
    }
}

// ------- fused softmax + aggregation + bias + ReLU + sliced stats ------
// R6 staging + R10 sliced-stats epilogue; inner loop deepened to 16
// outstanding gathers (dual accumulators) for more memory-level parallelism.
__global__ __launch_bounds__(256) void gat_aggregate(
    const int* __restrict__ rowptr, const int* __restrict__ esrc,
    const float* __restrict__ S, const float* __restrict__ D,
    const unsigned short* __restrict__ XWb, const float* __restrict__ bias,
    unsigned short* __restrict__ Hb, float* __restrict__ stp)
{
    __shared__ int   sbuf[4][64];
    __shared__ float wbuf[4][64][4];
    __shared__ float red_s[4][F];
    __shared__ float red_q[4][F];
    const int wv   = threadIdx.x >> 6;
    const int lane = threadIdx.x & 63;
    const int dst  = blockIdx.x * 4 + wv;        // always < N_NODES (N%4==0)
    const int beg = rowptr[dst], end = rowptr[dst + 1];
    const int h = lane >> 4;
    const float4 d4 = *reinterpret_cast<const float4*>(D + dst * HEADS);

    float axa = 0.f, aya = 0.f, aza = 0.f, awa = 0.f, dena = 0.f;
    float axb = 0.f, ayb = 0.f, azb = 0.f, awb = 0.f, denb = 0.f;

    for (int i = beg; i < end; i += 64) {
        const int nb = min(64, end - i);
        const bool valid = (i + lane < end);
        const int mysrc = valid ? esrc[i + lane] : 0;   // row 0 always valid
        float4 w4 = {0.f, 0.f, 0.f, 0.f};
        if (valid) {
            const float4 s4 = *reinterpret_cast<const float4*>(S + mysrc * HEADS);
            float z;
            z = s4.x + d4.x; w4.x = __expf(z > 0.f ? z : NEG_SLOPE * z);
            z = s4.y + d4.y; w4.y = __expf(z > 0.f ? z : NEG_SLOPE * z);
            z = s4.z + d4.z; w4.z = __expf(z > 0.f ? z : NEG_SLOPE * z);
            z = s4.w + d4.w; w4.w = __expf(z > 0.f ? z : NEG_SLOPE * z);
        }
        sbuf[wv][lane] = mysrc;
        *reinterpret_cast<float4*>(&wbuf[wv][lane][0]) = w4;

        int j = 0;
        for (; j + 15 < nb; j += 16) {
            int ss[16]; float ww[16]; ushort4 xx[16];
#pragma unroll
            for (int u = 0; u < 16; u++) {
                ss[u] = sbuf[wv][j + u];
                ww[u] = wbuf[wv][j + u][h];
            }
#pragma unroll
            for (int u = 0; u < 16; u++)
                xx[u] = *reinterpret_cast<const ushort4*>(XWb + (size_t)ss[u] * F + lane * 4);
#pragma unroll
            for (int u = 0; u < 16; u += 2) {
                axa += ww[u] * bf2f(xx[u].x); aya += ww[u] * bf2f(xx[u].y);
                aza += ww[u] * bf2f(xx[u].z); awa += ww[u] * bf2f(xx[u].w);
                dena += ww[u];
                axb += ww[u+1] * bf2f(xx[u+1].x); ayb += ww[u+1] * bf2f(xx[u+1].y);
                azb += ww[u+1] * bf2f(xx[u+1].z); awb += ww[u+1] * bf2f(xx[u+1].w);
                denb += ww[u+1];
            }
        }
        for (; j + 7 < nb; j += 8) {
            int ss[8]; float ww[8]; ushort4 xx[8];
#pragma unroll
            for (int u = 0; u < 8; u++) {
                ss[u] = sbuf[wv][j + u];
                ww[u] = wbuf[wv][j + u][h];
            }
#pragma unroll
            for (int u = 0; u < 8; u++)
                xx[u] = *reinterpret_cast<const ushort4*>(XWb + (size_t)ss[u] * F + lane * 4);
#pragma unroll
            for (int u = 0; u < 8; u += 2) {
                axa += ww[u] * bf2f(xx[u].x); aya += ww[u] * bf2f(xx[u].y);
                aza += ww[u] * bf2f(xx[u].z); awa += ww[u] * bf2f(xx[u].w);
                dena += ww[u];
                axb += ww[u+1] * bf2f(xx[u+1].x); ayb += ww[u+1] * bf2f(xx[u+1].y);
                azb += ww[u+1] * bf2f(xx[u+1].z); awb += ww[u+1] * bf2f(xx[u+1].w);
                denb += ww[u+1];
            }
        }
        for (; j < nb; j++) {
            int   src = sbuf[wv][j];
            float w = wbuf[wv][j][h];
            ushort4 xv = *reinterpret_cast<const ushort4*>(XWb + (size_t)src * F + lane * 4);
            axa += w * bf2f(xv.x); aya += w * bf2f(xv.y);
            aza += w * bf2f(xv.z); awa += w * bf2f(xv.w);
            dena += w;
        }
    }

    const float ax = axa + axb, ay = aya + ayb, az = aza + azb, aw = awa + awb;
    const float den = dena + denb;
    const float inv = 1.f / (den + 1e-16f);
    float4 bv = *reinterpret_cast<const float4*>(bias + lane * 4);
    float v0 = ax * inv + bv.x, v1 = ay * inv + bv.y;
    float v2 = az * inv + bv.z, v3 = aw * inv + bv.w;
    v0 = v0 > 0.f ? v0 : 0.f; v1 = v1 > 0.f ? v1 : 0.f;
    v2 = v2 > 0.f ? v2 : 0.f; v3 = v3 > 0.f ? v3 : 0.f;
    ushort4 o = { f2bf(v0), f2bf(v1), f2bf(v2), f2bf(v3) };
    *reinterpret_cast<ushort4*>(Hb + (size_t)dst * F + lane * 4) = o;

    f32x4 rs = {v0, v1, v2, v3};
    f32x4 rq = {v0 * v0, v1 * v1, v2 * v2, v3 * v3};
    *reinterpret_cast<f32x4*>(&red_s[wv][lane * 4]) = rs;
    *reinterpret_cast<f32x4*>(&red_q[wv][lane * 4]) = rq;
    __syncthreads();
    // block stats -> SLICED atomics (spread contention NSLICE-ways)
    const int ch = threadIdx.x;
    float s = (red_s[0][ch] + red_s[1][ch]) + (red_s[2][ch] + red_s[3][ch]);
    float q = (red_q[0][ch] + red_q[1][ch]) + (red_q[2][ch] + red_q[3][ch]);
    float* slice = stp + (size_t)(blockIdx.x & (NSLICE - 1)) * (2 * F);
    atomicAdd(&slice[ch], s);
    atomicAdd(&slice[F + ch], q);
}

// ---- BN prep + brow (1 block, R10-proven; slice-sum input) ----
__global__ __launch_bounds__(256) void prep_brow(
    const float* __restrict__ stp, const float* __restrict__ g,
    const float* __restrict__ be, const float* __restrict__ W2,
    float* __restrict__ scb, float* __restrict__ shb, float* __restrict__ brow)
{
    __shared__ float sh_l[F];
    const int t = threadIdx.x;
    float s = 0.f, q = 0.f;
    for (int b = 0; b < NSLICE; b++) {       // fixed order
        s += stp[(size_t)b * 2 * F + t];
        q += stp[(size_t)b * 2 * F + F + t];
    }
    const float inv_n = 1.f / (float)N_NODES;
    float mu = s * inv_n;
    float var = q * inv_n - mu * mu;
    float sc = rsqrtf(var + BN_EPS) * g[t];
    float sh = be[t] - mu * sc;
    scb[t] = sc;
    shb[t] = sh;
    sh_l[t] = sh;
    __syncthreads();
    float acc = 0.f;
    for (int k = 0; k < F; k++)
        acc += sh_l[k] * W2[(size_t)k * F + t];
    brow[t] = acc;
}

// ---- fold BN1 into W2 (transposed bf16), 32 blocks (R10-proven) ----
__global__ __launch_bounds__(256) void fold_w2(
    const float* __restrict__ W2, const float* __restrict__ scb,
    unsigned short* __restrict__ WT2b)
{
    const int t = threadIdx.x;       // n
    const int k0 = blockIdx.x * 8;
#pragma unroll
    for (int kk = 0; kk < 8; kk++)
        WT2b[(size_t)t * F + k0 + kk] = f2bf(W2[(size_t)(k0 + kk) * F + t] * scb[k0 + kk]);
}

// ---------------- BN2 prep + fold into classifier weights, 1 block ----
__global__ __launch_bounds__(256) void fold_wc(
    const float* __restrict__ stp, const float* __restrict__ g,
    const float* __restrict__ be, const float* __restrict__ Wc,
    const float* __restrict__ bc, float* __restrict__ Wcp, float* __restrict__ bcp)
{
    __shared__ float sc_l[F], sh_l[F];
    const int t = threadIdx.x;
    float s = 0.f, q = 0.f;
    for (int b = 0; b < NSLICE; b++) {       // fixed order
        s += stp[(size_t)b * 2 * F + t];
        q += stp[(size_t)b * 2 * F + F + t];
    }
    const float inv_n = 1.f / (float)N_NODES;
    float mu = s * inv_n;
    float var = q * inv_n - mu * mu;
    float sc = rsqrtf(var + BN_EPS) * g[t];
    sc_l[t] = sc;
    sh_l[t] = be[t] - mu * sc;
    __syncthreads();
#pragma unroll
    for (int o = 0; o < OUTC; o++)
        Wcp[t * OUTC + o] = Wc[t * OUTC + o] * sc_l[t];
    if (t < OUTC) {
        float acc = bc[t];
        for (int kk = 0; kk < F; kk++)
            acc += sh_l[kk] * Wc[kk * OUTC + t];
        bcp[t] = acc;
    }
}

// ---------------- classifier: [N,256]bf16 @ Wcp[256,10] + bcp --------
__global__ __launch_bounds__(256) void classifier(
    const unsigned short* __restrict__ Hb, const float* __restrict__ Wcp,
    const float* __restrict__ bcp, float* __restrict__ out)
{
    __shared__ float wls[F][OUTC + 1];
    const int t = threadIdx.x;
    for (int i = t; i < F * OUTC; i += 256)
        wls[i / OUTC][i % OUTC] = Wcp[i];
    __syncthreads();

    const int wave = t >> 6, lane = t & 63;
    const int n = blockIdx.x * 4 + wave;
    if (n >= N_NODES) return;

    float v[4];
#pragma unroll
    for (int j = 0; j < 4; j++)
        v[j] = bf2f(Hb[(size_t)n * F + j * 64 + lane]);

    float acc[OUTC];
#pragma unroll
    for (int o = 0; o < OUTC; o++) acc[o] = 0.f;
#pragma unroll
    for (int j = 0; j < 4; j++)
#pragma unroll
        for (int o = 0; o < OUTC; o++)
            acc[o] += v[j] * wls[j * 64 + lane][o];

#pragma unroll
    for (int off = 32; off > 0; off >>= 1)
#pragma unroll
        for (int o = 0; o < OUTC; o++)
            acc[o] += __shfl_xor(acc[o], off, 64);

    if (lane == 0) {
#pragma unroll
        for (int o = 0; o < OUTC; o++)
            out[(size_t)n * OUTC + o] = acc[o] + bcp[o];
    }
}

extern "C" void kernel_launch(void* const* d_in, const int* in_sizes, int n_in,
                              void* d_out, int out_size, void* d_ws, size_t ws_size,
                              hipStream_t stream)
{
    const float* x   = (const float*)d_in[0];
    const int*   ei  = (const int*)d_in[1];
    const float* W1  = (const float*)d_in[2];
    const float* as1 = (const float*)d_in[3];
    const float* ad1 = (const float*)d_in[4];
    const float* b1  = (const float*)d_in[5];
    const float* W2  = (const float*)d_in[6];
    const float* as2 = (const float*)d_in[7];
    const float* ad2 = (const float*)d_in[8];
    const float* b2  = (const float*)d_in[9];
    const float* g1  = (const float*)d_in[10];
    const float* be1 = (const float*)d_in[11];
    const float* g2  = (const float*)d_in[12];
    const float* be2 = (const float*)d_in[13];
    const float* Wc  = (const float*)d_in[14];
    const float* bc  = (const float*)d_in[15];
    float* out = (float*)d_out;

    char* w = (char*)d_ws;
    // zero-init region first (one memset): deg | cursor | stp1 | stp2
    int*   deg   = (int*)w;                      w += (size_t)N_NODES * 4;
    int*   cursor= (int*)w;                      w += (size_t)N_NODES * 4;
    float* stp1  = (float*)w;                    w += (size_t)NSLICE * 2 * F * 4;
    float* stp2  = (float*)w;                    w += (size_t)NSLICE * 2 * F * 4;
    const size_t zero_bytes = (size_t)N_NODES * 8 + (size_t)NSLICE * 2 * F * 8;

    unsigned short* Xb   = (unsigned short*)w;   w += (size_t)N_NODES * 128 * 2;
    unsigned short* XWb  = (unsigned short*)w;   w += (size_t)N_NODES * F * 2;
    unsigned short* Hb   = (unsigned short*)w;   w += (size_t)N_NODES * F * 2;
    unsigned short* WT1b = (unsigned short*)w;   w += 256 * 128 * 2;
    unsigned short* WT2b = (unsigned short*)w;   w += 256 * 256 * 2;
    float* Wcp   = (float*)w;                    w += F * OUTC * 4;
    float* bcp   = (float*)w;                    w += 64;
    float* brow2 = (float*)w;                    w += F * 4;
    float* scb   = (float*)w;                    w += F * 4;
    float* shb   = (float*)w;                    w += F * 4;
    float* Sv    = (float*)w;                    w += (size_t)N_NODES * HEADS * 4;
    float* Dv    = (float*)w;                    w += (size_t)N_NODES * HEADS * 4;
    int* rowp    = (int*)w;                      w += (size_t)(N_NODES + 1) * 4;
    int* bsum    = (int*)w;                      w += NB * 4;
    int* esrc    = (int*)w;                      /* E2 ints */

    const int grid_e    = (E2 + 255) / 256;
    const int grid_nw   = N_NODES / 4;           // 12500, exact
    const int grid_gemm = (N_NODES + 63) / 64;   // 782
    const int grid_prep = CXB + CWB + CDB;       // 12824

    // ---- prep ----
    hipMemsetAsync(deg, 0, zero_bytes, stream);
    mega_prep<<<grid_prep, 256, 0, stream>>>(x, Xb, W1, WT1b, ei, deg);
    scan_blocks<<<NB, SB, 0, stream>>>(deg, rowp, bsum);
    scan_add2<<<NB, SB, 0, stream>>>(rowp, bsum);
    scatter_edges<<<grid_e, 256, 0, stream>>>(ei, rowp, cursor, esrc);

    // ---- layer 1 ----
    gemm_sd<128, false><<<grid_gemm, 256, 0, stream>>>(
        Xb, WT1b, nullptr, as1, ad1, XWb, Sv, Dv);
    gat_aggregate<<<grid_nw, 256, 0, stream>>>(rowp, esrc, Sv, Dv, XWb, b1, Hb, stp1);
    prep_brow<<<1, 256, 0, stream>>>(stp1, g1, be1, W2, scb, shb, brow2);
    fold_w2<<<32, 256, 0, stream>>>(W2, scb, WT2b);

    // ---- layer 2 ----
    gemm_sd<256, true><<<grid_gemm, 256, 0, stream>>>(
        Hb, WT2b, brow2, as2, ad2, XWb, Sv, Dv);
    gat_aggregate<<<grid_nw, 256, 0, stream>>>(rowp, esrc, Sv, Dv, XWb, b2, Hb, stp2);
    fold_wc<<<1, 256, 0, stream>>>(stp2, g2, be2, Wc, bc, Wcp, bcp);

    // ---- classifier ----
    classifier<<<grid_nw, 256, 0, stream>>>(Hb, Wcp, bcp, out);
}

// Round 14
// 562.627 us; speedup vs baseline: 1.1424x; 1.0044x over previous
//
#include <hip/hip_runtime.h>

#define N_NODES 50000
#define E_EDGES 1600000
#define E2 (E_EDGES + N_NODES)   // 1,650,000 with self loops
#define HEADS 4
#define F 256
#define OUTC 10
#define BN_EPS 1e-5f
#define NEG_SLOPE 0.2f
#define NSLICE 64                // stats atomic-spreading slices
#define SB 1024                  // scan block size
#define NB ((N_NODES + SB - 1) / SB)   // 49 scan blocks

// mega_prep block ranges
#define CXB (N_NODES * 128 / 4 / 256)        // 6250 convert_x blocks
#define CWB 128                               // convert_w1T blocks
#define CDB ((E2 + 255) / 256)                // 6446 count_deg blocks

static_assert(N_NODES % 4 == 0, "grid_nw exact");

typedef __attribute__((ext_vector_type(8))) short short8;
typedef __attribute__((ext_vector_type(4))) float f32x4;

__device__ __forceinline__ unsigned short f2bf(float f) {
    unsigned int u = __float_as_uint(f);
    unsigned int r = (u + 0x7fffu + ((u >> 16) & 1u)) >> 16;
    return (unsigned short)r;
}
__device__ __forceinline__ float bf2f(unsigned short b) {
    return __uint_as_float(((unsigned int)b) << 16);
}

// ---- fused prep: convert_x | convert_w1T | count_deg (branch on block) --
__global__ __launch_bounds__(256) void mega_prep(
    const float* __restrict__ X, unsigned short* __restrict__ Xb,
    const float* __restrict__ W1, unsigned short* __restrict__ WT,
    const int* __restrict__ eidx, int* __restrict__ deg)
{
    const int b = blockIdx.x;
    const int t = threadIdx.x;
    if (b < CXB) {
        const int i = b * 256 + t;                 // float4 index, exact
        float4 v = reinterpret_cast<const float4*>(X)[i];
        ushort4 o = { f2bf(v.x), f2bf(v.y), f2bf(v.z), f2bf(v.w) };
        reinterpret_cast<ushort4*>(Xb)[i] = o;
    } else if (b < CXB + CWB) {
        const int k = b - CXB;                     // W1 row
        WT[t * 128 + k] = f2bf(W1[k * 256 + t]);
    } else {
        const int e = (b - CXB - CWB) * 256 + t;
        if (e < E2) {
            int dst = (e < E_EDGES) ? eidx[E_EDGES + e] : e - E_EDGES;
            atomicAdd(&deg[dst], 1);
        }
    }
}

// ---- parallel scan, 2 dispatches (R10/R12-proven) ----
__global__ __launch_bounds__(SB) void scan_blocks(
    const int* __restrict__ deg, int* __restrict__ rowptr, int* __restrict__ bsum)
{
    __shared__ int sm[SB];
    const int t = threadIdx.x;
    const int idx = blockIdx.x * SB + t;
    int v = (idx < N_NODES) ? deg[idx] : 0;
    sm[t] = v;
    __syncthreads();
    for (int off = 1; off < SB; off <<= 1) {
        int u = (t >= off) ? sm[t - off] : 0;
        __syncthreads();
        sm[t] += u;
        __syncthreads();
    }
    if (idx < N_NODES) rowptr[idx] = sm[t] - v;   // exclusive within block
    if (t == SB - 1) bsum[blockIdx.x] = sm[t];
}

// each block redundantly computes its prefix of bsum (fixed order, <=49 adds)
__global__ __launch_bounds__(SB) void scan_add2(
    int* __restrict__ rowptr, const int* __restrict__ bsum)
{
    __shared__ int boff_s;
    if (threadIdx.x == 0) {
        int run = 0;
        for (int b = 0; b < (int)blockIdx.x; b++) run += bsum[b];
        boff_s = run;
        if (blockIdx.x == 0) {
            int tot = 0;
            for (int b = 0; b < NB; b++) tot += bsum[b];
            rowptr[N_NODES] = tot;
        }
    }
    __syncthreads();
    const int idx = blockIdx.x * SB + threadIdx.x;
    if (idx < N_NODES) rowptr[idx] += boff_s;
}

__global__ __launch_bounds__(256) void scatter_edges(
    const int* __restrict__ eidx, const int* __restrict__ rowptr,
    int* __restrict__ cursor, int* __restrict__ esrc)
{
    int e = blockIdx.x * blockDim.x + threadIdx.x;
    if (e >= E2) return;
    int src, dst;
    if (e < E_EDGES) { src = eidx[e]; dst = eidx[E_EDGES + e]; }
    else             { src = dst = e - E_EDGES; }
    int pos = atomicAdd(&cursor[dst], 1);
    esrc[rowptr[dst] + pos] = src;
}

// ------- MFMA GEMM + fused S/D: C = A@BT^T (+brow); S/D from f32 acc ---
template<int K, bool BROW>
__global__ __launch_bounds__(256) void gemm_sd(
    const unsigned short* __restrict__ A, const unsigned short* __restrict__ BT,
    const float* __restrict__ brow, const float* __restrict__ a_src,
    const float* __restrict__ a_dst, unsigned short* __restrict__ C,
    float* __restrict__ S, float* __restrict__ D)
{
    const int t = threadIdx.x;
    const int wave = t >> 6, lane = t & 63;
    const int lo = lane & 15, hi = lane >> 4;
    const int row0 = blockIdx.x * 64;
    const int nbase = wave * 64;

    int arow[4];
#pragma unroll
    for (int m = 0; m < 4; m++)
        arow[m] = min(row0 + m * 16 + lo, N_NODES - 1);   // never read unwritten ws

    f32x4 acc[4][4];
#pragma unroll
    for (int m = 0; m < 4; m++)
#pragma unroll
        for (int n = 0; n < 4; n++)
            acc[m][n] = (f32x4){0.f, 0.f, 0.f, 0.f};

    for (int k0 = 0; k0 < K; k0 += 32) {
        const int kk = k0 + hi * 8;
        short8 af[4], bfr[4];
#pragma unroll
        for (int m = 0; m < 4; m++)
            af[m] = *reinterpret_cast<const short8*>(A + (size_t)arow[m] * K + kk);
#pragma unroll
        for (int n = 0; n < 4; n++)
            bfr[n] = *reinterpret_cast<const short8*>(BT + (size_t)(nbase + n * 16 + lo) * K + kk);
#pragma unroll
        for (int m = 0; m < 4; m++)
#pragma unroll
            for (int n = 0; n < 4; n++)
                acc[m][n] = __builtin_amdgcn_mfma_f32_16x16x32_bf16(
                    af[m], bfr[n], acc[m][n], 0, 0, 0);
    }

    float bb[4], asv[4], adv[4];
#pragma unroll
    for (int n = 0; n < 4; n++) {
        int col = nbase + n * 16 + lo;
        bb[n]  = BROW ? brow[col] : 0.f;
        asv[n] = a_src[col];
        adv[n] = a_dst[col];
    }

#pragma unroll
    for (int m = 0; m < 4; m++) {
#pragma unroll
        for (int i = 0; i < 4; i++) {
            const int row = row0 + m * 16 + hi * 4 + i;
            const bool ok = row < N_NODES;
            float ps = 0.f, pd = 0.f;
#pragma unroll
            for (int n = 0; n < 4; n++) {
                float v = acc[m][n][i] + bb[n];
                ps += v * asv[n];
                pd += v * adv[n];
                if (ok) C[(size_t)row * F + nbase + n * 16 + lo] = f2bf(v);
            }
#pragma unroll
            for (int off = 1; off < 16; off <<= 1) {
                ps += __shfl_xor(ps, off, 64);
                pd += __shfl_xor(pd, off, 64);
            }
            if (lo == 0 && ok) {
                S[row * HEADS + wave] = ps;
                D[row * HEADS + wave] = pd;
            }
        }
    }
}

// ------- fused softmax + aggregation + bias + ReLU + sliced stats ------
// EXACT R10 kernel (measured 121.6 us): R6 8-deep inner loop + sliced
// stats epilogue. VGPR 44, occupancy ~52%.
__global__ __launch_bounds__(256) void gat_aggregate(
    const int* __restrict__ rowptr, const int* __restrict__ esrc,
    const float* __restrict__ S, const float* __restrict__ D,
    const unsigned short* __restrict__ XWb, const float* __restrict__ bias,
    unsigned short* __restrict__ Hb, float* __restrict__ stp)
{
    __shared__ int   sbuf[4][64];
    __shared__ float wbuf[4][64][4];
    __shared__ float red_s[4][F];
    __shared__ float red_q[4][F];
    const int wv   = threadIdx.x >> 6;
    const int lane = threadIdx.x & 63;
    const int dst  = blockIdx.x * 4 + wv;        // always < N_NODES (N%4==0)
    const int beg = rowptr[dst], end = rowptr[dst + 1];
    const int h = lane >> 4;
    const float4 d4 = *reinterpret_cast<const float4*>(D + dst * HEADS);

    float ax = 0.f, ay = 0.f, az = 0.f, aw = 0.f, den = 0.f;

    for (int i = beg; i < end; i += 64) {
        const int nb = min(64, end - i);
        const bool valid = (i + lane < end);
        const int mysrc = valid ? esrc[i + lane] : 0;   // row 0 always valid
        float4 w4 = {0.f, 0.f, 0.f, 0.f};
        if (valid) {
            const float4 s4 = *reinterpret_cast<const float4*>(S + mysrc * HEADS);
            float z;
            z = s4.x + d4.x; w4.x = __expf(z > 0.f ? z : NEG_SLOPE * z);
            z = s4.y + d4.y; w4.y = __expf(z > 0.f ? z : NEG_SLOPE * z);
            z = s4.z + d4.z; w4.z = __expf(z > 0.f ? z : NEG_SLOPE * z);
            z = s4.w + d4.w; w4.w = __expf(z > 0.f ? z : NEG_SLOPE * z);
        }
        sbuf[wv][lane] = mysrc;
        *reinterpret_cast<float4*>(&wbuf[wv][lane][0]) = w4;

        int j = 0;
        for (; j + 7 < nb; j += 8) {
            int s0 = sbuf[wv][j + 0], s1 = sbuf[wv][j + 1];
            int s2 = sbuf[wv][j + 2], s3 = sbuf[wv][j + 3];
            int s4i = sbuf[wv][j + 4], s5 = sbuf[wv][j + 5];
            int s6 = sbuf[wv][j + 6], s7 = sbuf[wv][j + 7];
            float w0 = wbuf[wv][j + 0][h], w1 = wbuf[wv][j + 1][h];
            float w2 = wbuf[wv][j + 2][h], w3 = wbuf[wv][j + 3][h];
            float w4f = wbuf[wv][j + 4][h], w5 = wbuf[wv][j + 5][h];
            float w6 = wbuf[wv][j + 6][h], w7 = wbuf[wv][j + 7][h];
            ushort4 x0 = *reinterpret_cast<const ushort4*>(XWb + (size_t)s0 * F + lane * 4);
            ushort4 x1 = *reinterpret_cast<const ushort4*>(XWb + (size_t)s1 * F + lane * 4);
            ushort4 x2 = *reinterpret_cast<const ushort4*>(XWb + (size_t)s2 * F + lane * 4);
            ushort4 x3 = *reinterpret_cast<const ushort4*>(XWb + (size_t)s3 * F + lane * 4);
            ushort4 x4 = *reinterpret_cast<const ushort4*>(XWb + (size_t)s4i * F + lane * 4);
            ushort4 x5 = *reinterpret_cast<const ushort4*>(XWb + (size_t)s5 * F + lane * 4);
            ushort4 x6 = *reinterpret_cast<const ushort4*>(XWb + (size_t)s6 * F + lane * 4);
            ushort4 x7 = *reinterpret_cast<const ushort4*>(XWb + (size_t)s7 * F + lane * 4);
            ax += w0 * bf2f(x0.x) + w1 * bf2f(x1.x) + w2 * bf2f(x2.x) + w3 * bf2f(x3.x)
                + w4f * bf2f(x4.x) + w5 * bf2f(x5.x) + w6 * bf2f(x6.x) + w7 * bf2f(x7.x);
            ay += w0 * bf2f(x0.y) + w1 * bf2f(x1.y) + w2 * bf2f(x2.y) + w3 * bf2f(x3.y)
                + w4f * bf2f(x4.y) + w5 * bf2f(x5.y) + w6 * bf2f(x6.y) + w7 * bf2f(x7.y);
            az += w0 * bf2f(x0.z) + w1 * bf2f(x1.z) + w2 * bf2f(x2.z) + w3 * bf2f(x3.z)
                + w4f * bf2f(x4.z) + w5 * bf2f(x5.z) + w6 * bf2f(x6.z) + w7 * bf2f(x7.z);
            aw += w0 * bf2f(x0.w) + w1 * bf2f(x1.w) + w2 * bf2f(x2.w) + w3 * bf2f(x3.w)
                + w4f * bf2f(x4.w) + w5 * bf2f(x5.w) + w6 * bf2f(x6.w) + w7 * bf2f(x7.w);
            den += ((w0 + w1) + (w2 + w3)) + ((w4f + w5) + (w6 + w7));
        }
        for (; j < nb; j++) {
            int   src = sbuf[wv][j];
            float w = wbuf[wv][j][h];
            ushort4 xv = *reinterpret_cast<const ushort4*>(XWb + (size_t)src * F + lane * 4);
            ax += w * bf2f(xv.x); ay += w * bf2f(xv.y);
            az += w * bf2f(xv.z); aw += w * bf2f(xv.w);
            den += w;
        }
    }

    const float inv = 1.f / (den + 1e-16f);
    float4 bv = *reinterpret_cast<const float4*>(bias + lane * 4);
    float v0 = ax * inv + bv.x, v1 = ay * inv + bv.y;
    float v2 = az * inv + bv.z, v3 = aw * inv + bv.w;
    v0 = v0 > 0.f ? v0 : 0.f; v1 = v1 > 0.f ? v1 : 0.f;
    v2 = v2 > 0.f ? v2 : 0.f; v3 = v3 > 0.f ? v3 : 0.f;
    ushort4 o = { f2bf(v0), f2bf(v1), f2bf(v2), f2bf(v3) };
    *reinterpret_cast<ushort4*>(Hb + (size_t)dst * F + lane * 4) = o;

    f32x4 rs = {v0, v1, v2, v3};
    f32x4 rq = {v0 * v0, v1 * v1, v2 * v2, v3 * v3};
    *reinterpret_cast<f32x4*>(&red_s[wv][lane * 4]) = rs;
    *reinterpret_cast<f32x4*>(&red_q[wv][lane * 4]) = rq;
    __syncthreads();
    // block stats -> SLICED atomics (spread contention NSLICE-ways)
    const int ch = threadIdx.x;
    float s = (red_s[0][ch] + red_s[1][ch]) + (red_s[2][ch] + red_s[3][ch]);
    float q = (red_q[0][ch] + red_q[1][ch]) + (red_q[2][ch] + red_q[3][ch]);
    float* slice = stp + (size_t)(blockIdx.x & (NSLICE - 1)) * (2 * F);
    atomicAdd(&slice[ch], s);
    atomicAdd(&slice[F + ch], q);
}

// ---- fold BN1 into W2 + brow, ONE kernel, 33 blocks ----
// Blocks 0-31: WT2b slab (8 k each); block 32: brow[n]=sum_k sh[k]W2[k,n].
// Every block recomputes sc/sh from stp redundantly (fixed order ->
// deterministic; proven costless in R12's fold_w2b).
__global__ __launch_bounds__(256) void fold1(
    const float* __restrict__ stp, const float* __restrict__ g,
    const float* __restrict__ be, const float* __restrict__ W2,
    unsigned short* __restrict__ WT2b, float* __restrict__ brow)
{
    __shared__ float sc_l[F], sh_l[F];
    const int t = threadIdx.x;
    float s = 0.f, q = 0.f;
    for (int b = 0; b < NSLICE; b++) {       // fixed order
        s += stp[(size_t)b * 2 * F + t];
        q += stp[(size_t)b * 2 * F + F + t];
    }
    const float inv_n = 1.f / (float)N_NODES;
    float mu = s * inv_n;
    float var = q * inv_n - mu * mu;
    float sc = rsqrtf(var + BN_EPS) * g[t];
    sc_l[t] = sc;
    sh_l[t] = be[t] - mu * sc;
    __syncthreads();
    if (blockIdx.x < 32) {
        const int k0 = blockIdx.x * 8;
#pragma unroll
        for (int kk = 0; kk < 8; kk++)
            WT2b[(size_t)t * F + k0 + kk] = f2bf(W2[(size_t)(k0 + kk) * F + t] * sc_l[k0 + kk]);
    } else {
        float acc = 0.f;
        for (int k = 0; k < F; k++)          // coalesced across t, fixed order
            acc += sh_l[k] * W2[(size_t)k * F + t];
        brow[t] = acc;
    }
}

// ---- BN2 prep + fold into classifier weights, 1 block ----
// bcp computed by ALL 256 threads (partials) + fixed-order LDS tree reduce.
__global__ __launch_bounds__(256) void fold_wc(
    const float* __restrict__ stp, const float* __restrict__ g,
    const float* __restrict__ be, const float* __restrict__ Wc,
    const float* __restrict__ bc, float* __restrict__ Wcp, float* __restrict__ bcp)
{
    __shared__ float sc_l[F], sh_l[F];
    __shared__ float red[256][OUTC];
    const int t = threadIdx.x;
    float s = 0.f, q = 0.f;
    for (int b = 0; b < NSLICE; b++) {       // fixed order
        s += stp[(size_t)b * 2 * F + t];
        q += stp[(size_t)b * 2 * F + F + t];
    }
    const float inv_n = 1.f / (float)N_NODES;
    float mu = s * inv_n;
    float var = q * inv_n - mu * mu;
    float sc = rsqrtf(var + BN_EPS) * g[t];
    sc_l[t] = sc;
    sh_l[t] = be[t] - mu * sc;
    // per-thread partials for bcp
    const float sh_t = be[t] - mu * sc;
#pragma unroll
    for (int o = 0; o < OUTC; o++) {
        float wv = Wc[t * OUTC + o];
        Wcp[t * OUTC + o] = wv * sc;
        red[t][o] = sh_t * wv;
    }
    __syncthreads();
    // fixed-order tree reduce over 256 threads -> deterministic
    for (int off = 128; off > 0; off >>= 1) {
        if (t < off) {
#pragma unroll
            for (int o = 0; o < OUTC; o++)
                red[t][o] += red[t + off][o];
        }
        __syncthreads();
    }
    if (t < OUTC) bcp[t] = bc[t] + red[0][t];
}

// ---------------- classifier: [N,256]bf16 @ Wcp[256,10] + bcp --------
__global__ __launch_bounds__(256) void classifier(
    const unsigned short* __restrict__ Hb, const float* __restrict__ Wcp,
    const float* __restrict__ bcp, float* __restrict__ out)
{
    __shared__ float wls[F][OUTC + 1];
    const int t = threadIdx.x;
    for (int i = t; i < F * OUTC; i += 256)
        wls[i / OUTC][i % OUTC] = Wcp[i];
    __syncthreads();

    const int wave = t >> 6, lane = t & 63;
    const int n = blockIdx.x * 4 + wave;
    if (n >= N_NODES) return;

    float v[4];
#pragma unroll
    for (int j = 0; j < 4; j++)
        v[j] = bf2f(Hb[(size_t)n * F + j * 64 + lane]);

    float acc[OUTC];
#pragma unroll
    for (int o = 0; o < OUTC; o++) acc[o] = 0.f;
#pragma unroll
    for (int j = 0; j < 4; j++)
#pragma unroll
        for (int o = 0; o < OUTC; o++)
            acc[o] += v[j] * wls[j * 64 + lane][o];

#pragma unroll
    for (int off = 32; off > 0; off >>= 1)
#pragma unroll
        for (int o = 0; o < OUTC; o++)
            acc[o] += __shfl_xor(acc[o], off, 64);

    if (lane == 0) {
#pragma unroll
        for (int o = 0; o < OUTC; o++)
            out[(size_t)n * OUTC + o] = acc[o] + bcp[o];
    }
}

extern "C" void kernel_launch(void* const* d_in, const int* in_sizes, int n_in,
                              void* d_out, int out_size, void* d_ws, size_t ws_size,
                              hipStream_t stream)
{
    const float* x   = (const float*)d_in[0];
    const int*   ei  = (const int*)d_in[1];
    const float* W1  = (const float*)d_in[2];
    const float* as1 = (const float*)d_in[3];
    const float* ad1 = (const float*)d_in[4];
    const float* b1  = (const float*)d_in[5];
    const float* W2  = (const float*)d_in[6];
    const float* as2 = (const float*)d_in[7];
    const float* ad2 = (const float*)d_in[8];
    const float* b2  = (const float*)d_in[9];
    const float* g1  = (const float*)d_in[10];
    const float* be1 = (const float*)d_in[11];
    const float* g2  = (const float*)d_in[12];
    const float* be2 = (const float*)d_in[13];
    const float* Wc  = (const float*)d_in[14];
    const float* bc  = (const float*)d_in[15];
    float* out = (float*)d_out;

    char* w = (char*)d_ws;
    // zero-init region first (one memset): deg | cursor | stp1 | stp2
    int*   deg   = (int*)w;                      w += (size_t)N_NODES * 4;
    int*   cursor= (int*)w;                      w += (size_t)N_NODES * 4;
    float* stp1  = (float*)w;                    w += (size_t)NSLICE * 2 * F * 4;
    float* stp2  = (float*)w;                    w += (size_t)NSLICE * 2 * F * 4;
    const size_t zero_bytes = (size_t)N_NODES * 8 + (size_t)NSLICE * 2 * F * 8;

    unsigned short* Xb   = (unsigned short*)w;   w += (size_t)N_NODES * 128 * 2;
    unsigned short* XWb  = (unsigned short*)w;   w += (size_t)N_NODES * F * 2;
    unsigned short* Hb   = (unsigned short*)w;   w += (size_t)N_NODES * F * 2;
    unsigned short* WT1b = (unsigned short*)w;   w += 256 * 128 * 2;
    unsigned short* WT2b = (unsigned short*)w;   w += 256 * 256 * 2;
    float* Wcp   = (float*)w;                    w += F * OUTC * 4;
    float* bcp   = (float*)w;                    w += 64;
    float* brow2 = (float*)w;                    w += F * 4;
    float* Sv    = (float*)w;                    w += (size_t)N_NODES * HEADS * 4;
    float* Dv    = (float*)w;                    w += (size_t)N_NODES * HEADS * 4;
    int* rowp    = (int*)w;                      w += (size_t)(N_NODES + 1) * 4;
    int* bsum    = (int*)w;                      w += NB * 4;
    int* esrc    = (int*)w;                      /* E2 ints */

    const int grid_e    = (E2 + 255) / 256;
    const int grid_nw   = N_NODES / 4;           // 12500, exact
    const int grid_gemm = (N_NODES + 63) / 64;   // 782
    const int grid_prep = CXB + CWB + CDB;       // 12824

    // ---- prep ----
    hipMemsetAsync(deg, 0, zero_bytes, stream);
    mega_prep<<<grid_prep, 256, 0, stream>>>(x, Xb, W1, WT1b, ei, deg);
    scan_blocks<<<NB, SB, 0, stream>>>(deg, rowp, bsum);
    scan_add2<<<NB, SB, 0, stream>>>(rowp, bsum);
    scatter_edges<<<grid_e, 256, 0, stream>>>(ei, rowp, cursor, esrc);

    // ---- layer 1 ----
    gemm_sd<128, false><<<grid_gemm, 256, 0, stream>>>(
        Xb, WT1b, nullptr, as1, ad1, XWb, Sv, Dv);
    gat_aggregate<<<grid_nw, 256, 0, stream>>>(rowp, esrc, Sv, Dv, XWb, b1, Hb, stp1);
    fold1<<<33, 256, 0, stream>>>(stp1, g1, be1, W2, WT2b, brow2);

    // ---- layer 2 ----
    gemm_sd<256, true><<<grid_gemm, 256, 0, stream>>>(
        Hb, WT2b, brow2, as2, ad2, XWb, Sv, Dv);
    gat_aggregate<<<grid_nw, 256, 0, stream>>>(rowp, esrc, Sv, Dv, XWb, b2, Hb, stp2);
    fold_wc<<<1, 256, 0, stream>>>(stp2, g2, be2, Wc, bc, Wcp, bcp);

    // ---- classifier ----
    classifier<<<grid_nw, 256, 0, stream>>>(Hb, Wcp, bcp, out);
}

// Round 15
// 532.874 us; speedup vs baseline: 1.2062x; 1.0558x over previous
//
#include <hip/hip_runtime.h>

#define N_NODES 50000
#define E_EDGES 1600000
#define E2 (E_EDGES + N_NODES)   // 1,650,000 with self loops
#define HEADS 4
#define F 256
#define OUTC 10
#define BN_EPS 1e-5f
#define NEG_SLOPE 0.2f
#define NSLICE 64                // stats atomic-spreading slices
#define SB 1024                  // scan block size
#define NB ((N_NODES + SB - 1) / SB)   // 49 scan blocks

// XCD-ranged edge processing (scatter + count): 8 dst-ranges
#define NXCD 8
#define NR (N_NODES / NXCD)                  // 6250 nodes per range
#define EPB 2048                             // edges per block-chunk
#define NCHUNK ((E2 + EPB - 1) / EPB)        // 806 chunks

// mega_prep block ranges
#define CXB (N_NODES * 128 / 4 / 256)        // 6250 convert_x blocks
#define CWB 128                               // convert_w1T blocks
#define CDB (NXCD * NCHUNK)                   // 6448 ranged count_deg blocks

static_assert(N_NODES % (4) == 0, "grid_nw exact");
static_assert(N_NODES % NXCD == 0, "ranges exact");

typedef __attribute__((ext_vector_type(8))) short short8;
typedef __attribute__((ext_vector_type(4))) float f32x4;

__device__ __forceinline__ unsigned short f2bf(float f) {
    unsigned int u = __float_as_uint(f);
    unsigned int r = (u + 0x7fffu + ((u >> 16) & 1u)) >> 16;
    return (unsigned short)r;
}
__device__ __forceinline__ float bf2f(unsigned short b) {
    return __uint_as_float(((unsigned int)b) << 16);
}

// ---- fused prep: convert_x | convert_w1T | ranged count_deg ----
// count_deg blocks: range r = (b-CXB-CWB)&7 -> XCD r (round-robin
// heuristic); only counts dst in [r*NR,(r+1)*NR) so deg-slice atomics
// stay in one XCD's L2.
__global__ __launch_bounds__(256) void mega_prep(
    const float* __restrict__ X, unsigned short* __restrict__ Xb,
    const float* __restrict__ W1, unsigned short* __restrict__ WT,
    const int* __restrict__ eidx, int* __restrict__ deg)
{
    const int b = blockIdx.x;
    const int t = threadIdx.x;
    if (b < CXB) {
        const int i = b * 256 + t;                 // float4 index, exact
        float4 v = reinterpret_cast<const float4*>(X)[i];
        ushort4 o = { f2bf(v.x), f2bf(v.y), f2bf(v.z), f2bf(v.w) };
        reinterpret_cast<ushort4*>(Xb)[i] = o;
    } else if (b < CXB + CWB) {
        const int k = b - CXB;                     // W1 row
        WT[t * 128 + k] = f2bf(W1[k * 256 + t]);
    } else {
        const int b2 = b - CXB - CWB;
        const int r = b2 & (NXCD - 1);
        const int chunk = b2 >> 3;
        const int lo = r * NR;
        const int base = chunk * EPB;
        for (int i = t; i < EPB; i += 256) {
            const int e = base + i;
            if (e >= E2) break;
            int dst = (e < E_EDGES) ? eidx[E_EDGES + e] : e - E_EDGES;
            if ((unsigned)(dst - lo) >= (unsigned)NR) continue;
            atomicAdd(&deg[dst], 1);
        }
    }
}

// ---- parallel scan, 2 dispatches (R10/R12-proven) ----
__global__ __launch_bounds__(SB) void scan_blocks(
    const int* __restrict__ deg, int* __restrict__ rowptr, int* __restrict__ bsum)
{
    __shared__ int sm[SB];
    const int t = threadIdx.x;
    const int idx = blockIdx.x * SB + t;
    int v = (idx < N_NODES) ? deg[idx] : 0;
    sm[t] = v;
    __syncthreads();
    for (int off = 1; off < SB; off <<= 1) {
        int u = (t >= off) ? sm[t - off] : 0;
        __syncthreads();
        sm[t] += u;
        __syncthreads();
    }
    if (idx < N_NODES) rowptr[idx] = sm[t] - v;   // exclusive within block
    if (t == SB - 1) bsum[blockIdx.x] = sm[t];
}

// each block redundantly computes its prefix of bsum (fixed order, <=49 adds)
__global__ __launch_bounds__(SB) void scan_add2(
    int* __restrict__ rowptr, const int* __restrict__ bsum)
{
    __shared__ int boff_s;
    if (threadIdx.x == 0) {
        int run = 0;
        for (int b = 0; b < (int)blockIdx.x; b++) run += bsum[b];
        boff_s = run;
        if (blockIdx.x == 0) {
            int tot = 0;
            for (int b = 0; b < NB; b++) tot += bsum[b];
            rowptr[N_NODES] = tot;
        }
    }
    __syncthreads();
    const int idx = blockIdx.x * SB + threadIdx.x;
    if (idx < N_NODES) rowptr[idx] += boff_s;
}

// ---- ranged scatter: block (r=b&7, chunk=b>>3) writes only dst-range r.
// esrc slice (825KB) + cursor slice (25KB) stay in XCD r's L2 -> the
// 64B-line RMW amplification (R14: 102MB WRITE_SIZE) is absorbed.
__global__ __launch_bounds__(256) void scatter_edges8(
    const int* __restrict__ eidx, const int* __restrict__ rowptr,
    int* __restrict__ cursor, int* __restrict__ esrc)
{
    const int r = blockIdx.x & (NXCD - 1);
    const int chunk = blockIdx.x >> 3;
    const int lo = r * NR;
    const int base = chunk * EPB;
    for (int i = threadIdx.x; i < EPB; i += 256) {
        const int e = base + i;
        if (e >= E2) break;
        int dst = (e < E_EDGES) ? eidx[E_EDGES + e] : e - E_EDGES;
        if ((unsigned)(dst - lo) >= (unsigned)NR) continue;
        int src = (e < E_EDGES) ? eidx[e] : dst;
        int pos = atomicAdd(&cursor[dst], 1);
        esrc[rowptr[dst] + pos] = src;
    }
}

// ------- MFMA GEMM + fused S/D: C = A@BT^T (+brow); S/D from f32 acc ---
template<int K, bool BROW>
__global__ __launch_bounds__(256) void gemm_sd(
    const unsigned short* __restrict__ A, const unsigned short* __restrict__ BT,
    const float* __restrict__ brow, const float* __restrict__ a_src,
    const float* __restrict__ a_dst, unsigned short* __restrict__ C,
    float* __restrict__ S, float* __restrict__ D)
{
    const int t = threadIdx.x;
    const int wave = t >> 6, lane = t & 63;
    const int lo = lane & 15, hi = lane >> 4;
    const int row0 = blockIdx.x * 64;
    const int nbase = wave * 64;

    int arow[4];
#pragma unroll
    for (int m = 0; m < 4; m++)
        arow[m] = min(row0 + m * 16 + lo, N_NODES - 1);   // never read unwritten ws

    f32x4 acc[4][4];
#pragma unroll
    for (int m = 0; m < 4; m++)
#pragma unroll
        for (int n = 0; n < 4; n++)
            acc[m][n] = (f32x4){0.f, 0.f, 0.f, 0.f};

    for (int k0 = 0; k0 < K; k0 += 32) {
        const int kk = k0 + hi * 8;
        short8 af[4], bfr[4];
#pragma unroll
        for (int m = 0; m < 4; m++)
            af[m] = *reinterpret_cast<const short8*>(A + (size_t)arow[m] * K + kk);
#pragma unroll
        for (int n = 0; n < 4; n++)
            bfr[n] = *reinterpret_cast<const short8*>(BT + (size_t)(nbase + n * 16 + lo) * K + kk);
#pragma unroll
        for (int m = 0; m < 4; m++)
#pragma unroll
            for (int n = 0; n < 4; n++)
                acc[m][n] = __builtin_amdgcn_mfma_f32_16x16x32_bf16(
                    af[m], bfr[n], acc[m][n], 0, 0, 0);
    }

    float bb[4], asv[4], adv[4];
#pragma unroll
    for (int n = 0; n < 4; n++) {
        int col = nbase + n * 16 + lo;
        bb[n]  = BROW ? brow[col] : 0.f;
        asv[n] = a_src[col];
        adv[n] = a_dst[col];
    }

#pragma unroll
    for (int m = 0; m < 4; m++) {
#pragma unroll
        for (int i = 0; i < 4; i++) {
            const int row = row0 + m * 16 + hi * 4 + i;
            const bool ok = row < N_NODES;
            float ps = 0.f, pd = 0.f;
#pragma unroll
            for (int n = 0; n < 4; n++) {
                float v = acc[m][n][i] + bb[n];
                ps += v * asv[n];
                pd += v * adv[n];
                if (ok) C[(size_t)row * F + nbase + n * 16 + lo] = f2bf(v);
            }
#pragma unroll
            for (int off = 1; off < 16; off <<= 1) {
                ps += __shfl_xor(ps, off, 64);
                pd += __shfl_xor(pd, off, 64);
            }
            if (lo == 0 && ok) {
                S[row * HEADS + wave] = ps;
                D[row * HEADS + wave] = pd;
            }
        }
    }
}

// ------- fused softmax + aggregation + bias + ReLU + sliced stats ------
// EXACT R10 kernel (measured 121.6 us / R14 119.9 us).
__global__ __launch_bounds__(256) void gat_aggregate(
    const int* __restrict__ rowptr, const int* __restrict__ esrc,
    const float* __restrict__ S, const float* __restrict__ D,
    const unsigned short* __restrict__ XWb, const float* __restrict__ bias,
    unsigned short* __restrict__ Hb, float* __restrict__ stp)
{
    __shared__ int   sbuf[4][64];
    __shared__ float wbuf[4][64][4];
    __shared__ float red_s[4][F];
    __shared__ float red_q[4][F];
    const int wv   = threadIdx.x >> 6;
    const int lane = threadIdx.x & 63;
    const int dst  = blockIdx.x * 4 + wv;        // always < N_NODES (N%4==0)
    const int beg = rowptr[dst], end = rowptr[dst + 1];
    const int h = lane >> 4;
    const float4 d4 = *reinterpret_cast<const float4*>(D + dst * HEADS);

    float ax = 0.f, ay = 0.f, az = 0.f, aw = 0.f, den = 0.f;

    for (int i = beg; i < end; i += 64) {
        const int nb = min(64, end - i);
        const bool valid = (i + lane < end);
        const int mysrc = valid ? esrc[i + lane] : 0;   // row 0 always valid
        float4 w4 = {0.f, 0.f, 0.f, 0.f};
        if (valid) {
            const float4 s4 = *reinterpret_cast<const float4*>(S + mysrc * HEADS);
            float z;
            z = s4.x + d4.x; w4.x = __expf(z > 0.f ? z : NEG_SLOPE * z);
            z = s4.y + d4.y; w4.y = __expf(z > 0.f ? z : NEG_SLOPE * z);
            z = s4.z + d4.z; w4.z = __expf(z > 0.f ? z : NEG_SLOPE * z);
            z = s4.w + d4.w; w4.w = __expf(z > 0.f ? z : NEG_SLOPE * z);
        }
        sbuf[wv][lane] = mysrc;
        *reinterpret_cast<float4*>(&wbuf[wv][lane][0]) = w4;

        int j = 0;
        for (; j + 7 < nb; j += 8) {
            int s0 = sbuf[wv][j + 0], s1 = sbuf[wv][j + 1];
            int s2 = sbuf[wv][j + 2], s3 = sbuf[wv][j + 3];
            int s4i = sbuf[wv][j + 4], s5 = sbuf[wv][j + 5];
            int s6 = sbuf[wv][j + 6], s7 = sbuf[wv][j + 7];
            float w0 = wbuf[wv][j + 0][h], w1 = wbuf[wv][j + 1][h];
            float w2 = wbuf[wv][j + 2][h], w3 = wbuf[wv][j + 3][h];
            float w4f = wbuf[wv][j + 4][h], w5 = wbuf[wv][j + 5][h];
            float w6 = wbuf[wv][j + 6][h], w7 = wbuf[wv][j + 7][h];
            ushort4 x0 = *reinterpret_cast<const ushort4*>(XWb + (size_t)s0 * F + lane * 4);
            ushort4 x1 = *reinterpret_cast<const ushort4*>(XWb + (size_t)s1 * F + lane * 4);
            ushort4 x2 = *reinterpret_cast<const ushort4*>(XWb + (size_t)s2 * F + lane * 4);
            ushort4 x3 = *reinterpret_cast<const ushort4*>(XWb + (size_t)s3 * F + lane * 4);
            ushort4 x4 = *reinterpret_cast<const ushort4*>(XWb + (size_t)s4i * F + lane * 4);
            ushort4 x5 = *reinterpret_cast<const ushort4*>(XWb + (size_t)s5 * F + lane * 4);
            ushort4 x6 = *reinterpret_cast<const ushort4*>(XWb + (size_t)s6 * F + lane * 4);
            ushort4 x7 = *reinterpret_cast<const ushort4*>(XWb + (size_t)s7 * F + lane * 4);
            ax += w0 * bf2f(x0.x) + w1 * bf2f(x1.x) + w2 * bf2f(x2.x) + w3 * bf2f(x3.x)
                + w4f * bf2f(x4.x) + w5 * bf2f(x5.x) + w6 * bf2f(x6.x) + w7 * bf2f(x7.x);
            ay += w0 * bf2f(x0.y) + w1 * bf2f(x1.y) + w2 * bf2f(x2.y) + w3 * bf2f(x3.y)
                + w4f * bf2f(x4.y) + w5 * bf2f(x5.y) + w6 * bf2f(x6.y) + w7 * bf2f(x7.y);
            az += w0 * bf2f(x0.z) + w1 * bf2f(x1.z) + w2 * bf2f(x2.z) + w3 * bf2f(x3.z)
                + w4f * bf2f(x4.z) + w5 * bf2f(x5.z) + w6 * bf2f(x6.z) + w7 * bf2f(x7.z);
            aw += w0 * bf2f(x0.w) + w1 * bf2f(x1.w) + w2 * bf2f(x2.w) + w3 * bf2f(x3.w)
                + w4f * bf2f(x4.w) + w5 * bf2f(x5.w) + w6 * bf2f(x6.w) + w7 * bf2f(x7.w);
            den += ((w0 + w1) + (w2 + w3)) + ((w4f + w5) + (w6 + w7));
        }
        for (; j < nb; j++) {
            int   src = sbuf[wv][j];
            float w = wbuf[wv][j][h];
            ushort4 xv = *reinterpret_cast<const ushort4*>(XWb + (size_t)src * F + lane * 4);
            ax += w * bf2f(xv.x); ay += w * bf2f(xv.y);
            az += w * bf2f(xv.z); aw += w * bf2f(xv.w);
            den += w;
        }
    }

    const float inv = 1.f / (den + 1e-16f);
    float4 bv = *reinterpret_cast<const float4*>(bias + lane * 4);
    float v0 = ax * inv + bv.x, v1 = ay * inv + bv.y;
    float v2 = az * inv + bv.z, v3 = aw * inv + bv.w;
    v0 = v0 > 0.f ? v0 : 0.f; v1 = v1 > 0.f ? v1 : 0.f;
    v2 = v2 > 0.f ? v2 : 0.f; v3 = v3 > 0.f ? v3 : 0.f;
    ushort4 o = { f2bf(v0), f2bf(v1), f2bf(v2), f2bf(v3) };
    *reinterpret_cast<ushort4*>(Hb + (size_t)dst * F + lane * 4) = o;

    f32x4 rs = {v0, v1, v2, v3};
    f32x4 rq = {v0 * v0, v1 * v1, v2 * v2, v3 * v3};
    *reinterpret_cast<f32x4*>(&red_s[wv][lane * 4]) = rs;
    *reinterpret_cast<f32x4*>(&red_q[wv][lane * 4]) = rq;
    __syncthreads();
    // block stats -> SLICED atomics (spread contention NSLICE-ways)
    const int ch = threadIdx.x;
    float s = (red_s[0][ch] + red_s[1][ch]) + (red_s[2][ch] + red_s[3][ch]);
    float q = (red_q[0][ch] + red_q[1][ch]) + (red_q[2][ch] + red_q[3][ch]);
    float* slice = stp + (size_t)(blockIdx.x & (NSLICE - 1)) * (2 * F);
    atomicAdd(&slice[ch], s);
    atomicAdd(&slice[F + ch], q);
}

// ---- fold BN1 into W2 + brow, ONE kernel, 33 blocks (R14-proven) ----
__global__ __launch_bounds__(256) void fold1(
    const float* __restrict__ stp, const float* __restrict__ g,
    const float* __restrict__ be, const float* __restrict__ W2,
    unsigned short* __restrict__ WT2b, float* __restrict__ brow)
{
    __shared__ float sc_l[F], sh_l[F];
    const int t = threadIdx.x;
    float s = 0.f, q = 0.f;
    for (int b = 0; b < NSLICE; b++) {       // fixed order
        s += stp[(size_t)b * 2 * F + t];
        q += stp[(size_t)b * 2 * F + F + t];
    }
    const float inv_n = 1.f / (float)N_NODES;
    float mu = s * inv_n;
    float var = q * inv_n - mu * mu;
    float sc = rsqrtf(var + BN_EPS) * g[t];
    sc_l[t] = sc;
    sh_l[t] = be[t] - mu * sc;
    __syncthreads();
    if (blockIdx.x < 32) {
        const int k0 = blockIdx.x * 8;
#pragma unroll
        for (int kk = 0; kk < 8; kk++)
            WT2b[(size_t)t * F + k0 + kk] = f2bf(W2[(size_t)(k0 + kk) * F + t] * sc_l[k0 + kk]);
    } else {
        float acc = 0.f;
        for (int k = 0; k < F; k++)          // coalesced across t, fixed order
            acc += sh_l[k] * W2[(size_t)k * F + t];
        brow[t] = acc;
    }
}

// ---- BN2 prep + fold into classifier weights, 1 block (R14-proven) ----
__global__ __launch_bounds__(256) void fold_wc(
    const float* __restrict__ stp, const float* __restrict__ g,
    const float* __restrict__ be, const float* __restrict__ Wc,
    const float* __restrict__ bc, float* __restrict__ Wcp, float* __restrict__ bcp)
{
    __shared__ float sc_l[F], sh_l[F];
    __shared__ float red[256][OUTC];
    const int t = threadIdx.x;
    float s = 0.f, q = 0.f;
    for (int b = 0; b < NSLICE; b++) {       // fixed order
        s += stp[(size_t)b * 2 * F + t];
        q += stp[(size_t)b * 2 * F + F + t];
    }
    const float inv_n = 1.f / (float)N_NODES;
    float mu = s * inv_n;
    float var = q * inv_n - mu * mu;
    float sc = rsqrtf(var + BN_EPS) * g[t];
    sc_l[t] = sc;
    sh_l[t] = be[t] - mu * sc;
    const float sh_t = be[t] - mu * sc;
#pragma unroll
    for (int o = 0; o < OUTC; o++) {
        float wv = Wc[t * OUTC + o];
        Wcp[t * OUTC + o] = wv * sc;
        red[t][o] = sh_t * wv;
    }
    __syncthreads();
    for (int off = 128; off > 0; off >>= 1) {
        if (t < off) {
#pragma unroll
            for (int o = 0; o < OUTC; o++)
                red[t][o] += red[t + off][o];
        }
        __syncthreads();
    }
    if (t < OUTC) bcp[t] = bc[t] + red[0][t];
}

// ---------------- classifier: [N,256]bf16 @ Wcp[256,10] + bcp --------
__global__ __launch_bounds__(256) void classifier(
    const unsigned short* __restrict__ Hb, const float* __restrict__ Wcp,
    const float* __restrict__ bcp, float* __restrict__ out)
{
    __shared__ float wls[F][OUTC + 1];
    const int t = threadIdx.x;
    for (int i = t; i < F * OUTC; i += 256)
        wls[i / OUTC][i % OUTC] = Wcp[i];
    __syncthreads();

    const int wave = t >> 6, lane = t & 63;
    const int n = blockIdx.x * 4 + wave;
    if (n >= N_NODES) return;

    float v[4];
#pragma unroll
    for (int j = 0; j < 4; j++)
        v[j] = bf2f(Hb[(size_t)n * F + j * 64 + lane]);

    float acc[OUTC];
#pragma unroll
    for (int o = 0; o < OUTC; o++) acc[o] = 0.f;
#pragma unroll
    for (int j = 0; j < 4; j++)
#pragma unroll
        for (int o = 0; o < OUTC; o++)
            acc[o] += v[j] * wls[j * 64 + lane][o];

#pragma unroll
    for (int off = 32; off > 0; off >>= 1)
#pragma unroll
        for (int o = 0; o < OUTC; o++)
            acc[o] += __shfl_xor(acc[o], off, 64);

    if (lane == 0) {
#pragma unroll
        for (int o = 0; o < OUTC; o++)
            out[(size_t)n * OUTC + o] = acc[o] + bcp[o];
    }
}

extern "C" void kernel_launch(void* const* d_in, const int* in_sizes, int n_in,
                              void* d_out, int out_size, void* d_ws, size_t ws_size,
                              hipStream_t stream)
{
    const float* x   = (const float*)d_in[0];
    const int*   ei  = (const int*)d_in[1];
    const float* W1  = (const float*)d_in[2];
    const float* as1 = (const float*)d_in[3];
    const float* ad1 = (const float*)d_in[4];
    const float* b1  = (const float*)d_in[5];
    const float* W2  = (const float*)d_in[6];
    const float* as2 = (const float*)d_in[7];
    const float* ad2 = (const float*)d_in[8];
    const float* b2  = (const float*)d_in[9];
    const float* g1  = (const float*)d_in[10];
    const float* be1 = (const float*)d_in[11];
    const float* g2  = (const float*)d_in[12];
    const float* be2 = (const float*)d_in[13];
    const float* Wc  = (const float*)d_in[14];
    const float* bc  = (const float*)d_in[15];
    float* out = (float*)d_out;

    char* w = (char*)d_ws;
    // zero-init region first (one memset): deg | cursor | stp1 | stp2
    int*   deg   = (int*)w;                      w += (size_t)N_NODES * 4;
    int*   cursor= (int*)w;                      w += (size_t)N_NODES * 4;
    float* stp1  = (float*)w;                    w += (size_t)NSLICE * 2 * F * 4;
    float* stp2  = (float*)w;                    w += (size_t)NSLICE * 2 * F * 4;
    const size_t zero_bytes = (size_t)N_NODES * 8 + (size_t)NSLICE * 2 * F * 8;

    unsigned short* Xb   = (unsigned short*)w;   w += (size_t)N_NODES * 128 * 2;
    unsigned short* XWb  = (unsigned short*)w;   w += (size_t)N_NODES * F * 2;
    unsigned short* Hb   = (unsigned short*)w;   w += (size_t)N_NODES * F * 2;
    unsigned short* WT1b = (unsigned short*)w;   w += 256 * 128 * 2;
    unsigned short* WT2b = (unsigned short*)w;   w += 256 * 256 * 2;
    float* Wcp   = (float*)w;                    w += F * OUTC * 4;
    float* bcp   = (float*)w;                    w += 64;
    float* brow2 = (float*)w;                    w += F * 4;
    float* Sv    = (float*)w;                    w += (size_t)N_NODES * HEADS * 4;
    float* Dv    = (float*)w;                    w += (size_t)N_NODES * HEADS * 4;
    int* rowp    = (int*)w;                      w += (size_t)(N_NODES + 1) * 4;
    int* bsum    = (int*)w;                      w += NB * 4;
    int* esrc    = (int*)w;                      /* E2 ints */

    const int grid_nw   = N_NODES / 4;           // 12500, exact
    const int grid_gemm = (N_NODES + 63) / 64;   // 782
    const int grid_prep = CXB + CWB + CDB;       // 12826
    const int grid_sc   = NXCD * NCHUNK;         // 6448

    // ---- prep ----
    hipMemsetAsync(deg, 0, zero_bytes, stream);
    mega_prep<<<grid_prep, 256, 0, stream>>>(x, Xb, W1, WT1b, ei, deg);
    scan_blocks<<<NB, SB, 0, stream>>>(deg, rowp, bsum);
    scan_add2<<<NB, SB, 0, stream>>>(rowp, bsum);
    scatter_edges8<<<grid_sc, 256, 0, stream>>>(ei, rowp, cursor, esrc);

    // ---- layer 1 ----
    gemm_sd<128, false><<<grid_gemm, 256, 0, stream>>>(
        Xb, WT1b, nullptr, as1, ad1, XWb, Sv, Dv);
    gat_aggregate<<<grid_nw, 256, 0, stream>>>(rowp, esrc, Sv, Dv, XWb, b1, Hb, stp1);
    fold1<<<33, 256, 0, stream>>>(stp1, g1, be1, W2, WT2b, brow2);

    // ---- layer 2 ----
    gemm_sd<256, true><<<grid_gemm, 256, 0, stream>>>(
        Hb, WT2b, brow2, as2, ad2, XWb, Sv, Dv);
    gat_aggregate<<<grid_nw, 256, 0, stream>>>(rowp, esrc, Sv, Dv, XWb, b2, Hb, stp2);
    fold_wc<<<1, 256, 0, stream>>>(stp2, g2, be2, Wc, bc, Wcp, bcp);

    // ---- classifier ----
    classifier<<<grid_nw, 256, 0, stream>>>(Hb, Wcp, bcp, out);
}